// Round 3
// baseline (37651.462 us; speedup 1.0000x reference)
//
#include <hip/hip_runtime.h>
#include <hip/hip_bf16.h>
#include <math.h>

typedef __hip_bfloat16 bf16;

#define BB 8
#define NN 2048
#define KK 20

// ---- workspace layout (float offsets) ----
#define O_XMAN  0                        // [8][19][2048]
#define O_XC1   311296                   // [8][83][2048]
#define O_XC2   1671168                  // [8][512][2048] (rows 0..255 = x_mlp, 256..511 = xp2)
#define O_IDX2  10059776                 // int [8][2048][20]
#define O_IDX3  10387456                 // int [8][2048][20]
#define O_MLPW  10715136                 // [256][20] padded
#define O_MLPSC 10720256
#define O_MLPSH 10720512
#define O_W1P   10720768                 // [64][64] padded
#define O_BN1SC 10724864
#define O_BN1SH 10724928
#define O_P1SC  10724992
#define O_P1SH  10725056
#define O_P1W   10725120                 // [64][64]
#define O_P1B   10729216
#define O_W2P   10729280                 // [256][256] padded
#define O_BN2SC 10794816
#define O_BN2SH 10795072
#define O_P2SC  10795328
#define O_P2SH  10795584
#define O_P2W   10795840                 // [256][256]
#define O_P2B   10861376
#define O_W3P   10861632                 // [512][512]
#define O_BN3SC 11123776
#define O_BN3SH 11124288
#define O_LA    11124800                 // w1[48] b1[16] w2[48] b2[16] w3[16] b3[1]
#define O_FLAG  11124960                 // int: 1 if inputs are fp32, 0 if bf16

__device__ __forceinline__ float ldin(const void* p, int i, int f32) {
    return f32 ? ((const float*)p)[i]
               : __bfloat162float(((const bf16*)p)[i]);
}

// top-k insertion, jax tie semantics (strict >, stable among equals)
__device__ inline void topk_ins(float* tv, int* ti, float& minv, float d, int m) {
    if (d > minv) {
        int p = KK - 1;
        while (p > 0 && tv[p-1] < d) { tv[p] = tv[p-1]; ti[p] = ti[p-1]; --p; }
        tv[p] = d; ti[p] = m;
        minv = tv[KK-1];
    }
}

// ============ detect: are inputs fp32 or bf16? ============
__global__ void detect_kernel(const void* x, int* flag) {
    if (threadIdx.x == 0 && blockIdx.x == 0) {
        const unsigned short* u = (const unsigned short*)x;
        int bad = 0;
        for (int i = 0; i < 64; ++i) {
            int e = (u[i] >> 7) & 0xFF;
            if (e >= 0x86) bad++;       // |v| >= 64 or inf/nan: implausible for N(0,1) bf16
        }
        *flag = (bad > 0) ? 1 : 0;
    }
}

// ================= prep: inputs -> fp32, pad, fold BN =================
__global__ void prep_kernel(
    const void* la_w1, const void* la_b1, const void* la_w2, const void* la_b2,
    const void* la_w3, const void* la_b3,
    const void* mlp_w, const void* mlp_b, const void* mlp_bn,
    const void* w1, const void* bn1, const void* w2, const void* bn2,
    const void* w3, const void* bn3,
    const void* p1_bn, const void* p1_w, const void* p1_b,
    const void* p2_bn, const void* p2_w, const void* p2_b,
    float* ws)
{
    const int f32 = ((const int*)ws)[O_FLAG];
    int gid = blockIdx.x * blockDim.x + threadIdx.x;
    int gsz = gridDim.x * blockDim.x;

    for (int i = gid; i < 256*20; i += gsz) {
        int o = i / 20, c = i - o*20;
        ws[O_MLPW + i] = (c < 19) ? ldin(mlp_w, o*19 + c, f32) : 0.f;
    }
    for (int c = gid; c < 256; c += gsz) {
        float g = ldin(mlp_bn, c, f32), be = ldin(mlp_bn, 256+c, f32);
        float m = ldin(mlp_bn, 512+c, f32), vv = ldin(mlp_bn, 768+c, f32);
        float s = g / sqrtf(vv + 1e-5f);
        ws[O_MLPSC + c] = s;
        ws[O_MLPSH + c] = be + (ldin(mlp_b, c, f32) - m) * s;
    }
    for (int i = gid; i < 64*64; i += gsz) {
        int o = i >> 6, c = i & 63;
        ws[O_W1P + i] = (c < 57) ? ldin(w1, o*57 + c, f32) : 0.f;
    }
    for (int c = gid; c < 64; c += gsz) {
        float g = ldin(bn1, c, f32), be = ldin(bn1, 64+c, f32);
        float m = ldin(bn1, 128+c, f32), vv = ldin(bn1, 192+c, f32);
        float s = g / sqrtf(vv + 1e-5f);
        ws[O_BN1SC + c] = s; ws[O_BN1SH + c] = be - m*s;
        float g2 = ldin(p1_bn, c, f32), be2 = ldin(p1_bn, 64+c, f32);
        float m2 = ldin(p1_bn, 128+c, f32), vv2 = ldin(p1_bn, 192+c, f32);
        float s2 = g2 / sqrtf(vv2 + 1e-5f);
        ws[O_P1SC + c] = s2; ws[O_P1SH + c] = be2 - m2*s2;
        ws[O_P1B + c] = ldin(p1_b, c, f32);
    }
    for (int i = gid; i < 64*64; i += gsz) ws[O_P1W + i] = ldin(p1_w, i, f32);
    for (int i = gid; i < 256*256; i += gsz) {
        int o = i >> 8, c = i & 255;
        ws[O_W2P + i] = (c < 249) ? ldin(w2, o*249 + c, f32) : 0.f;
    }
    for (int c = gid; c < 256; c += gsz) {
        float g = ldin(bn2, c, f32), be = ldin(bn2, 256+c, f32);
        float m = ldin(bn2, 512+c, f32), vv = ldin(bn2, 768+c, f32);
        float s = g / sqrtf(vv + 1e-5f);
        ws[O_BN2SC + c] = s; ws[O_BN2SH + c] = be - m*s;
        float g2 = ldin(p2_bn, c, f32), be2 = ldin(p2_bn, 256+c, f32);
        float m2 = ldin(p2_bn, 512+c, f32), vv2 = ldin(p2_bn, 768+c, f32);
        float s2 = g2 / sqrtf(vv2 + 1e-5f);
        ws[O_P2SC + c] = s2; ws[O_P2SH + c] = be2 - m2*s2;
        ws[O_P2B + c] = ldin(p2_b, c, f32);
    }
    for (int i = gid; i < 256*256; i += gsz) ws[O_P2W + i] = ldin(p2_w, i, f32);
    for (int i = gid; i < 512*512; i += gsz) ws[O_W3P + i] = ldin(w3, i, f32);
    for (int c = gid; c < 512; c += gsz) {
        float g = ldin(bn3, c, f32), be = ldin(bn3, 512+c, f32);
        float m = ldin(bn3, 1024+c, f32), vv = ldin(bn3, 1536+c, f32);
        float s = g / sqrtf(vv + 1e-5f);
        ws[O_BN3SC + c] = s; ws[O_BN3SH + c] = be - m*s;
    }
    for (int i = gid; i < 48; i += gsz) ws[O_LA + i]       = ldin(la_w1, i, f32);
    for (int i = gid; i < 16; i += gsz) ws[O_LA + 48 + i]  = ldin(la_b1, i, f32);
    for (int i = gid; i < 48; i += gsz) ws[O_LA + 64 + i]  = ldin(la_w2, i, f32);
    for (int i = gid; i < 16; i += gsz) ws[O_LA + 112 + i] = ldin(la_b2, i, f32);
    for (int i = gid; i < 16; i += gsz) ws[O_LA + 128 + i] = ldin(la_w3, i, f32);
    if (gid == 0) ws[O_LA + 144] = ldin(la_b3, 0, f32);
}

// ================= lafe: knn(C=3) + local attention -> x_manet =================
__global__ void lafe_kernel(const void* x, float* ws) {
    __shared__ float xs0[NN], xs1[NN], xs2[NN], xxs[NN];
    const int f32 = ((const int*)ws)[O_FLAG];
    int tid = threadIdx.x;
    int b = blockIdx.x >> 3;
    int n = ((blockIdx.x & 7) << 8) + tid;
    int xoff = b * 3 * NN;
    for (int i = tid; i < NN; i += 256) {
        float v0 = ldin(x, xoff + i, f32);
        float v1 = ldin(x, xoff + NN + i, f32);
        float v2 = ldin(x, xoff + 2*NN + i, f32);
        xs0[i] = v0; xs1[i] = v1; xs2[i] = v2;
        xxs[i] = v0*v0 + v1*v1 + v2*v2;
    }
    __syncthreads();
    float a0 = xs0[n], a1 = xs1[n], a2 = xs2[n];
    float xxn = xxs[n];
    float tv[KK]; int ti[KK]; float minv = -3.0e38f;
    #pragma unroll
    for (int k = 0; k < KK; ++k) { tv[k] = -3.0e38f; ti[k] = 0; }
    for (int m = 0; m < NN; ++m) {
        float d = 2.f*(a0*xs0[m] + a1*xs1[m] + a2*xs2[m]) - xxn - xxs[m];
        topk_ins(tv, ti, minv, d, m);
    }
    const float* wl = ws + O_LA;
    float sa = wl[144];
    #pragma unroll
    for (int o = 0; o < 16; ++o) {
        float nf = wl[o*3+0]*a0 + wl[o*3+1]*a1 + wl[o*3+2]*a2 + wl[48+o];
        sa += wl[128+o]*nf;
    }
    float lg[KK]; float mx = -3.0e38f;
    #pragma unroll
    for (int k = 0; k < KK; ++k) {
        int m = ti[k] & (NN-1);
        float d0 = a0 - xs0[m], d1 = a1 - xs1[m], d2 = a2 - xs2[m];
        float na = wl[144];
        #pragma unroll
        for (int o = 0; o < 16; ++o) {
            float ef = wl[64+o*3+0]*d0 + wl[64+o*3+1]*d1 + wl[64+o*3+2]*d2 + wl[112+o];
            na += wl[128+o]*ef;
        }
        float t = sa + na;
        t = t > 0.f ? t : 0.01f*t;     // leaky 0.01
        lg[k] = t; mx = fmaxf(mx, t);
    }
    float ssum = 0.f;
    #pragma unroll
    for (int k = 0; k < KK; ++k) { lg[k] = expf(lg[k] - mx); ssum += lg[k]; }
    float vals[16];
    #pragma unroll
    for (int o = 0; o < 16; ++o) vals[o] = 0.f;
    #pragma unroll
    for (int k = 0; k < KK; ++k) {
        float coef = lg[k] / ssum;
        int m = ti[k] & (NN-1);
        float d0 = a0 - xs0[m], d1 = a1 - xs1[m], d2 = a2 - xs2[m];
        #pragma unroll
        for (int o = 0; o < 16; ++o) {
            float ef = wl[64+o*3+0]*d0 + wl[64+o*3+1]*d1 + wl[64+o*3+2]*d2 + wl[112+o];
            vals[o] += coef * ef;
        }
    }
    float* xm = ws + O_XMAN + b * 19 * NN;
    xm[0*NN + n] = a0; xm[1*NN + n] = a1; xm[2*NN + n] = a2;
    #pragma unroll
    for (int o = 0; o < 16; ++o) {
        float v = vals[o];
        xm[(3+o)*NN + n] = v > 0.f ? v : expm1f(v);   // elu
    }
}

// ================= generic knn on [B][C][N] fp32 -> idx [B][N][20] =================
template<int C, int TILE>
__global__ void knn_kernel(const float* feat, int* idxout) {
    __shared__ __align__(16) float tile[C * TILE + TILE];   // + xx at the end
    float* xxt = tile + C * TILE;
    int tid = threadIdx.x;
    int b = blockIdx.x >> 3;
    int n = ((blockIdx.x & 7) << 8) + tid;
    const float* fb = feat + b * C * NN;
    float myf[C];
    #pragma unroll
    for (int c = 0; c < C; ++c) myf[c] = fb[c*NN + n];
    float xxn = 0.f;
    #pragma unroll
    for (int c = 0; c < C; ++c) xxn += myf[c]*myf[c];
    float tv[KK]; int ti[KK]; float minv = -3.0e38f;
    #pragma unroll
    for (int k = 0; k < KK; ++k) { tv[k] = -3.0e38f; ti[k] = 0; }
    for (int t = 0; t < NN / TILE; ++t) {
        __syncthreads();
        for (int i = tid; i < C*TILE; i += 256) {
            int c = i / TILE, j = i - c*TILE;
            tile[i] = fb[c*NN + t*TILE + j];
        }
        __syncthreads();
        for (int j = tid; j < TILE; j += 256) {
            float s = 0.f;
            #pragma unroll
            for (int c = 0; c < C; ++c) s += tile[c*TILE + j]*tile[c*TILE + j];
            xxt[j] = s;
        }
        __syncthreads();
        for (int j4 = 0; j4 < TILE/4; ++j4) {
            float4 dot = make_float4(0.f, 0.f, 0.f, 0.f);
            #pragma unroll
            for (int c = 0; c < C; ++c) {
                float4 tvv = *(const float4*)&tile[c*TILE + j4*4];
                float f = myf[c];
                dot.x += f*tvv.x; dot.y += f*tvv.y; dot.z += f*tvv.z; dot.w += f*tvv.w;
            }
            float4 xxv = *(const float4*)&xxt[j4*4];
            int mb = t*TILE + j4*4;
            topk_ins(tv, ti, minv, 2.f*dot.x - xxn - xxv.x, mb+0);
            topk_ins(tv, ti, minv, 2.f*dot.y - xxn - xxv.y, mb+1);
            topk_ins(tv, ti, minv, 2.f*dot.z - xxn - xxv.z, mb+2);
            topk_ins(tv, ti, minv, 2.f*dot.w - xxn - xxv.w, mb+3);
        }
    }
    #pragma unroll
    for (int k = 0; k < KK; ++k) idxout[(b*NN + n)*KK + k] = ti[k];
}

// ================= mlp: x_mlp = relu(bn(W @ x_manet + b)) -> xc2 rows 0..255 =================
__global__ void mlp_kernel(float* ws) {
    __shared__ __align__(16) float xv[20];
    int tid = threadIdx.x;
    int b = blockIdx.x >> 11, n = blockIdx.x & 2047;
    if (tid < 20) xv[tid] = (tid < 19) ? ws[O_XMAN + b*19*NN + tid*NN + n] : 0.f;
    __syncthreads();
    const float* mw = ws + O_MLPW;
    float acc = 0.f;
    #pragma unroll
    for (int c4 = 0; c4 < 5; ++c4) {
        float4 w = *(const float4*)&mw[tid*20 + c4*4];
        float4 g = *(const float4*)&xv[c4*4];
        acc += w.x*g.x + w.y*g.y + w.z*g.z + w.w*g.w;
    }
    float v = acc * ws[O_MLPSC + tid] + ws[O_MLPSH + tid];
    ws[O_XC2 + b*512*NN + tid*NN + n] = fmaxf(v, 0.f);
}

// ================= edge1: h1 = lrelu(bn1(w1 @ g1)), att-pool p1 -> xc1 =================
__global__ void edge1_kernel(float* ws, const int* idx) {
    __shared__ __align__(16) float g1T[KK*64];
    __shared__ __align__(16) float h1L[64*21];
    __shared__ __align__(16) float hrT[KK*64];
    __shared__ __align__(16) float attL[64*21];
    __shared__ float xcL[19];
    __shared__ int idxL[KK];
    int tid = threadIdx.x;
    int b = blockIdx.x >> 11, n = blockIdx.x & 2047;
    const float* xb = ws + O_XMAN + b*19*NN;
    if (tid < KK) idxL[tid] = idx[(b*NN + n)*KK + tid] & (NN-1);
    if (tid < 19) xcL[tid] = xb[tid*NN + n];
    __syncthreads();
    for (int i = tid; i < KK*64; i += 64) {
        int k = i >> 6, c = i & 63;
        int j = idxL[k];
        float v = 0.f;
        if (c < 19) v = xb[c*NN + j];
        else if (c < 38) v = xcL[c-19];
        else if (c < 57) v = xcL[c-38] - xb[(c-38)*NN + j];
        g1T[i] = v;
    }
    __syncthreads();
    int ro = tid & 15, kb = (tid >> 4) * 5;
    const float* w1p = ws + O_W1P;
    float acc[4][5];
    #pragma unroll
    for (int j = 0; j < 4; ++j)
        #pragma unroll
        for (int kk = 0; kk < 5; ++kk) acc[j][kk] = 0.f;
    for (int c4 = 0; c4 < 16; ++c4) {
        float4 gv[5], wv[4];
        #pragma unroll
        for (int kk = 0; kk < 5; ++kk) gv[kk] = *(const float4*)&g1T[(kb+kk)*64 + c4*4];
        #pragma unroll
        for (int j = 0; j < 4; ++j) wv[j] = *(const float4*)&w1p[(ro + 16*j)*64 + c4*4];
        #pragma unroll
        for (int j = 0; j < 4; ++j)
            #pragma unroll
            for (int kk = 0; kk < 5; ++kk)
                acc[j][kk] += wv[j].x*gv[kk].x + wv[j].y*gv[kk].y + wv[j].z*gv[kk].z + wv[j].w*gv[kk].w;
    }
    #pragma unroll
    for (int j = 0; j < 4; ++j) {
        int r = ro + 16*j;
        float s1 = ws[O_BN1SC + r], h1s = ws[O_BN1SH + r];
        float ps = ws[O_P1SC + r], ph = ws[O_P1SH + r];
        #pragma unroll
        for (int kk = 0; kk < 5; ++kk) {
            float v = acc[j][kk]*s1 + h1s;
            v = v > 0.f ? v : 0.2f*v;
            h1L[r*21 + kb + kk] = v;
            float hv = v*ps + ph;
            hrT[(kb+kk)*64 + r] = hv > 0.f ? hv : 0.f;
        }
    }
    __syncthreads();
    const float* p1w = ws + O_P1W;
    float ac2[4][5];
    #pragma unroll
    for (int j = 0; j < 4; ++j)
        #pragma unroll
        for (int kk = 0; kk < 5; ++kk) ac2[j][kk] = 0.f;
    for (int c4 = 0; c4 < 16; ++c4) {
        float4 gv[5], wv[4];
        #pragma unroll
        for (int kk = 0; kk < 5; ++kk) gv[kk] = *(const float4*)&hrT[(kb+kk)*64 + c4*4];
        #pragma unroll
        for (int j = 0; j < 4; ++j) wv[j] = *(const float4*)&p1w[(ro + 16*j)*64 + c4*4];
        #pragma unroll
        for (int j = 0; j < 4; ++j)
            #pragma unroll
            for (int kk = 0; kk < 5; ++kk)
                ac2[j][kk] += wv[j].x*gv[kk].x + wv[j].y*gv[kk].y + wv[j].z*gv[kk].z + wv[j].w*gv[kk].w;
    }
    #pragma unroll
    for (int j = 0; j < 4; ++j) {
        int r = ro + 16*j;
        float pb = ws[O_P1B + r];
        #pragma unroll
        for (int kk = 0; kk < 5; ++kk) attL[r*21 + kb + kk] = ac2[j][kk] + pb;
    }
    __syncthreads();
    {
        int o = tid;   // 64 threads
        float av[KK]; float mx = -3.0e38f;
        #pragma unroll
        for (int k = 0; k < KK; ++k) { av[k] = attL[o*21 + k]; mx = fmaxf(mx, av[k]); }
        float ssum = 0.f;
        #pragma unroll
        for (int k = 0; k < KK; ++k) { av[k] = expf(av[k] - mx); ssum += av[k]; }
        float outv = 0.f;
        #pragma unroll
        for (int k = 0; k < KK; ++k) outv += h1L[o*21 + k] * (av[k]/ssum);
        float* xc1 = ws + O_XC1 + b*83*NN;
        xc1[(19+o)*NN + n] = outv;
        if (tid < 19) xc1[tid*NN + n] = xcL[tid];
    }
}

// ================= edge2: h2 = lrelu(bn2(w2 @ g2)), att-pool p2 -> xc2 rows 256..511 =================
__global__ void edge2_kernel(float* ws, const int* idx) {
    __shared__ __align__(16) float bufA[5376];      // g2T [20][256] then attL [256][21]
    __shared__ __align__(16) float h2L[256*21];
    __shared__ __align__(16) float hrT[KK*256];
    __shared__ float xcL[83];
    __shared__ int idxL[KK];
    int tid = threadIdx.x;
    int b = blockIdx.x >> 11, n = blockIdx.x & 2047;
    const float* xb = ws + O_XC1 + b*83*NN;
    if (tid < KK) idxL[tid] = idx[(b*NN + n)*KK + tid] & (NN-1);
    if (tid < 83) xcL[tid] = xb[tid*NN + n];
    __syncthreads();
    for (int i = tid; i < KK*256; i += 256) {
        int k = i >> 8, c = i & 255;
        int j = idxL[k];
        float v = 0.f;
        if (c < 83) v = xb[c*NN + j];
        else if (c < 166) v = xcL[c-83];
        else if (c < 249) v = xcL[c-166] - xb[(c-166)*NN + j];
        bufA[i] = v;
    }
    __syncthreads();
    int ro = tid & 63, kb = (tid >> 6) * 5;
    const float* w2p = ws + O_W2P;
    float acc[4][5];
    #pragma unroll
    for (int j = 0; j < 4; ++j)
        #pragma unroll
        for (int kk = 0; kk < 5; ++kk) acc[j][kk] = 0.f;
    for (int c4 = 0; c4 < 64; ++c4) {
        float4 gv[5], wv[4];
        #pragma unroll
        for (int kk = 0; kk < 5; ++kk) gv[kk] = *(const float4*)&bufA[(kb+kk)*256 + c4*4];
        #pragma unroll
        for (int j = 0; j < 4; ++j) wv[j] = *(const float4*)&w2p[(ro + 64*j)*256 + c4*4];
        #pragma unroll
        for (int j = 0; j < 4; ++j)
            #pragma unroll
            for (int kk = 0; kk < 5; ++kk)
                acc[j][kk] += wv[j].x*gv[kk].x + wv[j].y*gv[kk].y + wv[j].z*gv[kk].z + wv[j].w*gv[kk].w;
    }
    __syncthreads();  // all g2T reads done before bufA is reused as attL
    #pragma unroll
    for (int j = 0; j < 4; ++j) {
        int r = ro + 64*j;
        float s2 = ws[O_BN2SC + r], h2s = ws[O_BN2SH + r];
        float ps = ws[O_P2SC + r], ph = ws[O_P2SH + r];
        #pragma unroll
        for (int kk = 0; kk < 5; ++kk) {
            float v = acc[j][kk]*s2 + h2s;
            v = v > 0.f ? v : 0.2f*v;
            h2L[r*21 + kb + kk] = v;
            float hv = v*ps + ph;
            hrT[(kb+kk)*256 + r] = hv > 0.f ? hv : 0.f;
        }
    }
    __syncthreads();
    const float* p2w = ws + O_P2W;
    float ac2[4][5];
    #pragma unroll
    for (int j = 0; j < 4; ++j)
        #pragma unroll
        for (int kk = 0; kk < 5; ++kk) ac2[j][kk] = 0.f;
    for (int c4 = 0; c4 < 64; ++c4) {
        float4 gv[5], wv[4];
        #pragma unroll
        for (int kk = 0; kk < 5; ++kk) gv[kk] = *(const float4*)&hrT[(kb+kk)*256 + c4*4];
        #pragma unroll
        for (int j = 0; j < 4; ++j) wv[j] = *(const float4*)&p2w[(ro + 64*j)*256 + c4*4];
        #pragma unroll
        for (int j = 0; j < 4; ++j)
            #pragma unroll
            for (int kk = 0; kk < 5; ++kk)
                ac2[j][kk] += wv[j].x*gv[kk].x + wv[j].y*gv[kk].y + wv[j].z*gv[kk].z + wv[j].w*gv[kk].w;
    }
    __syncthreads();   // hrT reads done before bufA overwrite below
    #pragma unroll
    for (int j = 0; j < 4; ++j) {
        int r = ro + 64*j;
        float pb = ws[O_P2B + r];
        #pragma unroll
        for (int kk = 0; kk < 5; ++kk) bufA[r*21 + kb + kk] = ac2[j][kk] + pb;   // attL
    }
    __syncthreads();
    {
        int o = tid;   // 256
        float av[KK]; float mx = -3.0e38f;
        #pragma unroll
        for (int k = 0; k < KK; ++k) { av[k] = bufA[o*21 + k]; mx = fmaxf(mx, av[k]); }
        float ssum = 0.f;
        #pragma unroll
        for (int k = 0; k < KK; ++k) { av[k] = expf(av[k] - mx); ssum += av[k]; }
        float outv = 0.f;
        #pragma unroll
        for (int k = 0; k < KK; ++k) outv += h2L[o*21 + k] * (av[k]/ssum);
        ws[O_XC2 + b*512*NN + (256+o)*NN + n] = outv;
    }
}

// ================= final: out = lrelu(bn3(w3 @ x_c2)) -> fp32 =================
__global__ void final_kernel(const float* ws, float* out) {
    __shared__ __align__(16) float tileF[512*16];
    int tid = threadIdx.x;
    int b = blockIdx.x >> 7;
    int n0 = (blockIdx.x & 127) << 4;
    const float* xc2 = ws + O_XC2 + b*512*NN;
    for (int i = tid; i < 512*16; i += 256) {
        int c = i >> 4, nn = i & 15;
        tileF[i] = xc2[c*NN + n0 + nn];
    }
    __syncthreads();
    const float* w3p = ws + O_W3P;
    int r0 = tid*2, r1 = r0 + 1;
    float acc0[16], acc1[16];
    #pragma unroll
    for (int q = 0; q < 16; ++q) { acc0[q] = 0.f; acc1[q] = 0.f; }
    #pragma unroll 4
    for (int c = 0; c < 512; ++c) {
        float w0 = w3p[r0*512 + c], w1v = w3p[r1*512 + c];
        const float4* tr = (const float4*)&tileF[c*16];
        #pragma unroll
        for (int q = 0; q < 4; ++q) {
            float4 t = tr[q];
            acc0[q*4+0] += w0*t.x;  acc0[q*4+1] += w0*t.y;  acc0[q*4+2] += w0*t.z;  acc0[q*4+3] += w0*t.w;
            acc1[q*4+0] += w1v*t.x; acc1[q*4+1] += w1v*t.y; acc1[q*4+2] += w1v*t.z; acc1[q*4+3] += w1v*t.w;
        }
    }
    float s0 = ws[O_BN3SC + r0], q0 = ws[O_BN3SH + r0];
    float s1 = ws[O_BN3SC + r1], q1 = ws[O_BN3SH + r1];
    float* ob = out + b*512*NN;
    #pragma unroll
    for (int nn = 0; nn < 16; ++nn) {
        float v = acc0[nn]*s0 + q0; v = v > 0.f ? v : 0.2f*v;
        ob[r0*NN + n0 + nn] = v;
        float u = acc1[nn]*s1 + q1; u = u > 0.f ? u : 0.2f*u;
        ob[r1*NN + n0 + nn] = u;
    }
}

extern "C" void kernel_launch(void* const* d_in, const int* in_sizes, int n_in,
                              void* d_out, int out_size, void* d_ws, size_t ws_size,
                              hipStream_t stream) {
    float* ws = (float*)d_ws;
    float* out = (float*)d_out;

    detect_kernel<<<1, 64, 0, stream>>>(d_in[0], (int*)ws + O_FLAG);
    prep_kernel<<<64, 256, 0, stream>>>(d_in[1], d_in[2], d_in[3], d_in[4], d_in[5], d_in[6],
                                        d_in[7], d_in[8], d_in[9], d_in[10], d_in[11], d_in[12],
                                        d_in[13], d_in[14], d_in[15], d_in[16], d_in[17], d_in[18],
                                        d_in[19], d_in[20], d_in[21], ws);
    lafe_kernel<<<64, 256, 0, stream>>>(d_in[0], ws);
    knn_kernel<19, 256><<<64, 256, 0, stream>>>(ws + O_XMAN, (int*)(ws + O_IDX2));
    mlp_kernel<<<BB*NN, 256, 0, stream>>>(ws);
    edge1_kernel<<<BB*NN, 64, 0, stream>>>(ws, (const int*)(ws + O_IDX2));
    knn_kernel<83, 128><<<64, 256, 0, stream>>>(ws + O_XC1, (int*)(ws + O_IDX3));
    edge2_kernel<<<BB*NN, 256, 0, stream>>>(ws, (const int*)(ws + O_IDX3));
    final_kernel<<<BB*(NN/16), 256, 0, stream>>>(ws, out);
}

// Round 4
// 33365.616 us; speedup vs baseline: 1.1285x; 1.1285x over previous
//
#include <hip/hip_runtime.h>
#include <hip/hip_bf16.h>
#include <math.h>

typedef __hip_bfloat16 bf16;

#define BB 8
#define NN 2048
#define KK 20

// ---- workspace layout (float offsets) ----
#define O_XMAN  0                        // [8][19][2048]
#define O_XC1   311296                   // [8][83][2048]
#define O_XC2   1671168                  // [8][512][2048] (rows 0..255 = x_mlp, 256..511 = xp2)
#define O_IDX2  10059776                 // int [8][2048][20]
#define O_IDX3  10387456                 // int [8][2048][20]
#define O_MLPW  10715136                 // [256][20] padded
#define O_MLPSC 10720256
#define O_MLPSH 10720512
#define O_W1P   10720768                 // [64][64] padded
#define O_BN1SC 10724864
#define O_BN1SH 10724928
#define O_P1SC  10724992
#define O_P1SH  10725056
#define O_P1W   10725120                 // [64][64]
#define O_P1B   10729216
#define O_W2P   10729280                 // [256][256] padded
#define O_BN2SC 10794816
#define O_BN2SH 10795072
#define O_P2SC  10795328
#define O_P2SH  10795584
#define O_P2W   10795840                 // [256][256]
#define O_P2B   10861376
#define O_W3P   10861632                 // [512][512]
#define O_BN3SC 11123776
#define O_BN3SH 11124288
#define O_LA    11124800                 // w1[48] b1[16] w2[48] b2[16] w3[16] b3[1]
#define O_FLAG  11124960                 // int: 1 if inputs are fp32, 0 if bf16

__device__ __forceinline__ float ldin(const void* p, int i, int f32) {
    return f32 ? ((const float*)p)[i]
               : __bfloat162float(((const bf16*)p)[i]);
}

// top-k insertion with ONLY compile-time array indices (SROA keeps tv/ti in
// VGPRs; the round-3 version had a runtime-indexed shift loop -> scratch ->
// 11.5 GB of spill traffic per dispatch).
// jax tie semantics: strict > to displace the min; strict > to bubble past,
// so equal values keep the earlier (lower) index first.
__device__ __forceinline__ void topk_ins(float (&tv)[KK], int (&ti)[KK], float d, int m) {
    if (d > tv[KK-1]) {
        tv[KK-1] = d; ti[KK-1] = m;
        #pragma unroll
        for (int j = KK-1; j > 0; --j) {
            if (tv[j] > tv[j-1]) {
                float tf = tv[j-1]; tv[j-1] = tv[j]; tv[j] = tf;
                int   tx = ti[j-1]; ti[j-1] = ti[j]; ti[j] = tx;
            }
        }
    }
}

// ============ detect: are inputs fp32 or bf16? ============
__global__ void detect_kernel(const void* x, int* flag) {
    if (threadIdx.x == 0 && blockIdx.x == 0) {
        const unsigned short* u = (const unsigned short*)x;
        int bad = 0;
        for (int i = 0; i < 64; ++i) {
            int e = (u[i] >> 7) & 0xFF;
            if (e >= 0x86) bad++;       // |v| >= 64 or inf/nan: implausible for N(0,1) bf16
        }
        *flag = (bad > 0) ? 1 : 0;
    }
}

// ================= prep: inputs -> fp32, pad, fold BN =================
__global__ void prep_kernel(
    const void* la_w1, const void* la_b1, const void* la_w2, const void* la_b2,
    const void* la_w3, const void* la_b3,
    const void* mlp_w, const void* mlp_b, const void* mlp_bn,
    const void* w1, const void* bn1, const void* w2, const void* bn2,
    const void* w3, const void* bn3,
    const void* p1_bn, const void* p1_w, const void* p1_b,
    const void* p2_bn, const void* p2_w, const void* p2_b,
    float* ws)
{
    const int f32 = ((const int*)ws)[O_FLAG];
    int gid = blockIdx.x * blockDim.x + threadIdx.x;
    int gsz = gridDim.x * blockDim.x;

    for (int i = gid; i < 256*20; i += gsz) {
        int o = i / 20, c = i - o*20;
        ws[O_MLPW + i] = (c < 19) ? ldin(mlp_w, o*19 + c, f32) : 0.f;
    }
    for (int c = gid; c < 256; c += gsz) {
        float g = ldin(mlp_bn, c, f32), be = ldin(mlp_bn, 256+c, f32);
        float m = ldin(mlp_bn, 512+c, f32), vv = ldin(mlp_bn, 768+c, f32);
        float s = g / sqrtf(vv + 1e-5f);
        ws[O_MLPSC + c] = s;
        ws[O_MLPSH + c] = be + (ldin(mlp_b, c, f32) - m) * s;
    }
    for (int i = gid; i < 64*64; i += gsz) {
        int o = i >> 6, c = i & 63;
        ws[O_W1P + i] = (c < 57) ? ldin(w1, o*57 + c, f32) : 0.f;
    }
    for (int c = gid; c < 64; c += gsz) {
        float g = ldin(bn1, c, f32), be = ldin(bn1, 64+c, f32);
        float m = ldin(bn1, 128+c, f32), vv = ldin(bn1, 192+c, f32);
        float s = g / sqrtf(vv + 1e-5f);
        ws[O_BN1SC + c] = s; ws[O_BN1SH + c] = be - m*s;
        float g2 = ldin(p1_bn, c, f32), be2 = ldin(p1_bn, 64+c, f32);
        float m2 = ldin(p1_bn, 128+c, f32), vv2 = ldin(p1_bn, 192+c, f32);
        float s2 = g2 / sqrtf(vv2 + 1e-5f);
        ws[O_P1SC + c] = s2; ws[O_P1SH + c] = be2 - m2*s2;
        ws[O_P1B + c] = ldin(p1_b, c, f32);
    }
    for (int i = gid; i < 64*64; i += gsz) ws[O_P1W + i] = ldin(p1_w, i, f32);
    for (int i = gid; i < 256*256; i += gsz) {
        int o = i >> 8, c = i & 255;
        ws[O_W2P + i] = (c < 249) ? ldin(w2, o*249 + c, f32) : 0.f;
    }
    for (int c = gid; c < 256; c += gsz) {
        float g = ldin(bn2, c, f32), be = ldin(bn2, 256+c, f32);
        float m = ldin(bn2, 512+c, f32), vv = ldin(bn2, 768+c, f32);
        float s = g / sqrtf(vv + 1e-5f);
        ws[O_BN2SC + c] = s; ws[O_BN2SH + c] = be - m*s;
        float g2 = ldin(p2_bn, c, f32), be2 = ldin(p2_bn, 256+c, f32);
        float m2 = ldin(p2_bn, 512+c, f32), vv2 = ldin(p2_bn, 768+c, f32);
        float s2 = g2 / sqrtf(vv2 + 1e-5f);
        ws[O_P2SC + c] = s2; ws[O_P2SH + c] = be2 - m2*s2;
        ws[O_P2B + c] = ldin(p2_b, c, f32);
    }
    for (int i = gid; i < 256*256; i += gsz) ws[O_P2W + i] = ldin(p2_w, i, f32);
    for (int i = gid; i < 512*512; i += gsz) ws[O_W3P + i] = ldin(w3, i, f32);
    for (int c = gid; c < 512; c += gsz) {
        float g = ldin(bn3, c, f32), be = ldin(bn3, 512+c, f32);
        float m = ldin(bn3, 1024+c, f32), vv = ldin(bn3, 1536+c, f32);
        float s = g / sqrtf(vv + 1e-5f);
        ws[O_BN3SC + c] = s; ws[O_BN3SH + c] = be - m*s;
    }
    for (int i = gid; i < 48; i += gsz) ws[O_LA + i]       = ldin(la_w1, i, f32);
    for (int i = gid; i < 16; i += gsz) ws[O_LA + 48 + i]  = ldin(la_b1, i, f32);
    for (int i = gid; i < 48; i += gsz) ws[O_LA + 64 + i]  = ldin(la_w2, i, f32);
    for (int i = gid; i < 16; i += gsz) ws[O_LA + 112 + i] = ldin(la_b2, i, f32);
    for (int i = gid; i < 16; i += gsz) ws[O_LA + 128 + i] = ldin(la_w3, i, f32);
    if (gid == 0) ws[O_LA + 144] = ldin(la_b3, 0, f32);
}

// ================= lafe: knn(C=3) + local attention -> x_manet =================
__global__ void lafe_kernel(const void* x, float* ws) {
    __shared__ float xs0[NN], xs1[NN], xs2[NN], xxs[NN];
    const int f32 = ((const int*)ws)[O_FLAG];
    int tid = threadIdx.x;
    int b = blockIdx.x >> 3;
    int n = ((blockIdx.x & 7) << 8) + tid;
    int xoff = b * 3 * NN;
    for (int i = tid; i < NN; i += 256) {
        float v0 = ldin(x, xoff + i, f32);
        float v1 = ldin(x, xoff + NN + i, f32);
        float v2 = ldin(x, xoff + 2*NN + i, f32);
        xs0[i] = v0; xs1[i] = v1; xs2[i] = v2;
        xxs[i] = v0*v0 + v1*v1 + v2*v2;
    }
    __syncthreads();
    float a0 = xs0[n], a1 = xs1[n], a2 = xs2[n];
    float xxn = xxs[n];
    float tv[KK]; int ti[KK];
    #pragma unroll
    for (int k = 0; k < KK; ++k) { tv[k] = -3.0e38f; ti[k] = 0; }
    for (int m = 0; m < NN; ++m) {
        float d = 2.f*(a0*xs0[m] + a1*xs1[m] + a2*xs2[m]) - xxn - xxs[m];
        topk_ins(tv, ti, d, m);
    }
    const float* wl = ws + O_LA;
    float sa = wl[144];
    #pragma unroll
    for (int o = 0; o < 16; ++o) {
        float nf = wl[o*3+0]*a0 + wl[o*3+1]*a1 + wl[o*3+2]*a2 + wl[48+o];
        sa += wl[128+o]*nf;
    }
    float lg[KK]; float mx = -3.0e38f;
    #pragma unroll
    for (int k = 0; k < KK; ++k) {
        int m = ti[k] & (NN-1);
        float d0 = a0 - xs0[m], d1 = a1 - xs1[m], d2 = a2 - xs2[m];
        float na = wl[144];
        #pragma unroll
        for (int o = 0; o < 16; ++o) {
            float ef = wl[64+o*3+0]*d0 + wl[64+o*3+1]*d1 + wl[64+o*3+2]*d2 + wl[112+o];
            na += wl[128+o]*ef;
        }
        float t = sa + na;
        t = t > 0.f ? t : 0.01f*t;     // leaky 0.01
        lg[k] = t; mx = fmaxf(mx, t);
    }
    float ssum = 0.f;
    #pragma unroll
    for (int k = 0; k < KK; ++k) { lg[k] = expf(lg[k] - mx); ssum += lg[k]; }
    float vals[16];
    #pragma unroll
    for (int o = 0; o < 16; ++o) vals[o] = 0.f;
    #pragma unroll
    for (int k = 0; k < KK; ++k) {
        float coef = lg[k] / ssum;
        int m = ti[k] & (NN-1);
        float d0 = a0 - xs0[m], d1 = a1 - xs1[m], d2 = a2 - xs2[m];
        #pragma unroll
        for (int o = 0; o < 16; ++o) {
            float ef = wl[64+o*3+0]*d0 + wl[64+o*3+1]*d1 + wl[64+o*3+2]*d2 + wl[112+o];
            vals[o] += coef * ef;
        }
    }
    float* xm = ws + O_XMAN + b * 19 * NN;
    xm[0*NN + n] = a0; xm[1*NN + n] = a1; xm[2*NN + n] = a2;
    #pragma unroll
    for (int o = 0; o < 16; ++o) {
        float v = vals[o];
        xm[(3+o)*NN + n] = v > 0.f ? v : expm1f(v);   // elu
    }
}

// ================= generic knn on [B][C][N] fp32 -> idx [B][N][20] =================
template<int C, int TILE>
__global__ void knn_kernel(const float* feat, int* idxout) {
    __shared__ __align__(16) float tile[C * TILE + TILE];   // + xx at the end
    float* xxt = tile + C * TILE;
    int tid = threadIdx.x;
    int b = blockIdx.x >> 3;
    int n = ((blockIdx.x & 7) << 8) + tid;
    const float* fb = feat + b * C * NN;
    float myf[C];
    #pragma unroll
    for (int c = 0; c < C; ++c) myf[c] = fb[c*NN + n];
    float xxn = 0.f;
    #pragma unroll
    for (int c = 0; c < C; ++c) xxn += myf[c]*myf[c];
    float tv[KK]; int ti[KK];
    #pragma unroll
    for (int k = 0; k < KK; ++k) { tv[k] = -3.0e38f; ti[k] = 0; }
    for (int t = 0; t < NN / TILE; ++t) {
        __syncthreads();
        for (int i = tid; i < C*TILE; i += 256) {
            int c = i / TILE, j = i - c*TILE;
            tile[i] = fb[c*NN + t*TILE + j];
        }
        __syncthreads();
        for (int j = tid; j < TILE; j += 256) {
            float s = 0.f;
            #pragma unroll
            for (int c = 0; c < C; ++c) s += tile[c*TILE + j]*tile[c*TILE + j];
            xxt[j] = s;
        }
        __syncthreads();
        for (int j4 = 0; j4 < TILE/4; ++j4) {
            float4 dot = make_float4(0.f, 0.f, 0.f, 0.f);
            #pragma unroll
            for (int c = 0; c < C; ++c) {
                float4 tvv = *(const float4*)&tile[c*TILE + j4*4];
                float f = myf[c];
                dot.x += f*tvv.x; dot.y += f*tvv.y; dot.z += f*tvv.z; dot.w += f*tvv.w;
            }
            float4 xxv = *(const float4*)&xxt[j4*4];
            int mb = t*TILE + j4*4;
            topk_ins(tv, ti, 2.f*dot.x - xxn - xxv.x, mb+0);
            topk_ins(tv, ti, 2.f*dot.y - xxn - xxv.y, mb+1);
            topk_ins(tv, ti, 2.f*dot.z - xxn - xxv.z, mb+2);
            topk_ins(tv, ti, 2.f*dot.w - xxn - xxv.w, mb+3);
        }
    }
    #pragma unroll
    for (int k = 0; k < KK; ++k) idxout[(b*NN + n)*KK + k] = ti[k];
}

// ================= mlp: x_mlp = relu(bn(W @ x_manet + b)) -> xc2 rows 0..255 =================
__global__ void mlp_kernel(float* ws) {
    __shared__ __align__(16) float xv[20];
    int tid = threadIdx.x;
    int b = blockIdx.x >> 11, n = blockIdx.x & 2047;
    if (tid < 20) xv[tid] = (tid < 19) ? ws[O_XMAN + b*19*NN + tid*NN + n] : 0.f;
    __syncthreads();
    const float* mw = ws + O_MLPW;
    float acc = 0.f;
    #pragma unroll
    for (int c4 = 0; c4 < 5; ++c4) {
        float4 w = *(const float4*)&mw[tid*20 + c4*4];
        float4 g = *(const float4*)&xv[c4*4];
        acc += w.x*g.x + w.y*g.y + w.z*g.z + w.w*g.w;
    }
    float v = acc * ws[O_MLPSC + tid] + ws[O_MLPSH + tid];
    ws[O_XC2 + b*512*NN + tid*NN + n] = fmaxf(v, 0.f);
}

// ================= edge1: h1 = lrelu(bn1(w1 @ g1)), att-pool p1 -> xc1 =================
__global__ void edge1_kernel(float* ws, const int* idx) {
    __shared__ __align__(16) float g1T[KK*64];
    __shared__ __align__(16) float h1L[64*21];
    __shared__ __align__(16) float hrT[KK*64];
    __shared__ __align__(16) float attL[64*21];
    __shared__ float xcL[19];
    __shared__ int idxL[KK];
    int tid = threadIdx.x;
    int b = blockIdx.x >> 11, n = blockIdx.x & 2047;
    const float* xb = ws + O_XMAN + b*19*NN;
    if (tid < KK) idxL[tid] = idx[(b*NN + n)*KK + tid] & (NN-1);
    if (tid < 19) xcL[tid] = xb[tid*NN + n];
    __syncthreads();
    for (int i = tid; i < KK*64; i += 64) {
        int k = i >> 6, c = i & 63;
        int j = idxL[k];
        float v = 0.f;
        if (c < 19) v = xb[c*NN + j];
        else if (c < 38) v = xcL[c-19];
        else if (c < 57) v = xcL[c-38] - xb[(c-38)*NN + j];
        g1T[i] = v;
    }
    __syncthreads();
    int ro = tid & 15, kb = (tid >> 4) * 5;
    const float* w1p = ws + O_W1P;
    float acc[4][5];
    #pragma unroll
    for (int j = 0; j < 4; ++j)
        #pragma unroll
        for (int kk = 0; kk < 5; ++kk) acc[j][kk] = 0.f;
    for (int c4 = 0; c4 < 16; ++c4) {
        float4 gv[5], wv[4];
        #pragma unroll
        for (int kk = 0; kk < 5; ++kk) gv[kk] = *(const float4*)&g1T[(kb+kk)*64 + c4*4];
        #pragma unroll
        for (int j = 0; j < 4; ++j) wv[j] = *(const float4*)&w1p[(ro + 16*j)*64 + c4*4];
        #pragma unroll
        for (int j = 0; j < 4; ++j)
            #pragma unroll
            for (int kk = 0; kk < 5; ++kk)
                acc[j][kk] += wv[j].x*gv[kk].x + wv[j].y*gv[kk].y + wv[j].z*gv[kk].z + wv[j].w*gv[kk].w;
    }
    #pragma unroll
    for (int j = 0; j < 4; ++j) {
        int r = ro + 16*j;
        float s1 = ws[O_BN1SC + r], h1s = ws[O_BN1SH + r];
        float ps = ws[O_P1SC + r], ph = ws[O_P1SH + r];
        #pragma unroll
        for (int kk = 0; kk < 5; ++kk) {
            float v = acc[j][kk]*s1 + h1s;
            v = v > 0.f ? v : 0.2f*v;
            h1L[r*21 + kb + kk] = v;
            float hv = v*ps + ph;
            hrT[(kb+kk)*64 + r] = hv > 0.f ? hv : 0.f;
        }
    }
    __syncthreads();
    const float* p1w = ws + O_P1W;
    float ac2[4][5];
    #pragma unroll
    for (int j = 0; j < 4; ++j)
        #pragma unroll
        for (int kk = 0; kk < 5; ++kk) ac2[j][kk] = 0.f;
    for (int c4 = 0; c4 < 16; ++c4) {
        float4 gv[5], wv[4];
        #pragma unroll
        for (int kk = 0; kk < 5; ++kk) gv[kk] = *(const float4*)&hrT[(kb+kk)*64 + c4*4];
        #pragma unroll
        for (int j = 0; j < 4; ++j) wv[j] = *(const float4*)&p1w[(ro + 16*j)*64 + c4*4];
        #pragma unroll
        for (int j = 0; j < 4; ++j)
            #pragma unroll
            for (int kk = 0; kk < 5; ++kk)
                ac2[j][kk] += wv[j].x*gv[kk].x + wv[j].y*gv[kk].y + wv[j].z*gv[kk].z + wv[j].w*gv[kk].w;
    }
    #pragma unroll
    for (int j = 0; j < 4; ++j) {
        int r = ro + 16*j;
        float pb = ws[O_P1B + r];
        #pragma unroll
        for (int kk = 0; kk < 5; ++kk) attL[r*21 + kb + kk] = ac2[j][kk] + pb;
    }
    __syncthreads();
    {
        int o = tid;   // 64 threads
        float av[KK]; float mx = -3.0e38f;
        #pragma unroll
        for (int k = 0; k < KK; ++k) { av[k] = attL[o*21 + k]; mx = fmaxf(mx, av[k]); }
        float ssum = 0.f;
        #pragma unroll
        for (int k = 0; k < KK; ++k) { av[k] = expf(av[k] - mx); ssum += av[k]; }
        float outv = 0.f;
        #pragma unroll
        for (int k = 0; k < KK; ++k) outv += h1L[o*21 + k] * (av[k]/ssum);
        float* xc1 = ws + O_XC1 + b*83*NN;
        xc1[(19+o)*NN + n] = outv;
        if (tid < 19) xc1[tid*NN + n] = xcL[tid];
    }
}

// ================= edge2: h2 = lrelu(bn2(w2 @ g2)), att-pool p2 -> xc2 rows 256..511 =================
__global__ void edge2_kernel(float* ws, const int* idx) {
    __shared__ __align__(16) float bufA[5376];      // g2T [20][256] then attL [256][21]
    __shared__ __align__(16) float h2L[256*21];
    __shared__ __align__(16) float hrT[KK*256];
    __shared__ float xcL[83];
    __shared__ int idxL[KK];
    int tid = threadIdx.x;
    int b = blockIdx.x >> 11, n = blockIdx.x & 2047;
    const float* xb = ws + O_XC1 + b*83*NN;
    if (tid < KK) idxL[tid] = idx[(b*NN + n)*KK + tid] & (NN-1);
    if (tid < 83) xcL[tid] = xb[tid*NN + n];
    __syncthreads();
    for (int i = tid; i < KK*256; i += 256) {
        int k = i >> 8, c = i & 255;
        int j = idxL[k];
        float v = 0.f;
        if (c < 83) v = xb[c*NN + j];
        else if (c < 166) v = xcL[c-83];
        else if (c < 249) v = xcL[c-166] - xb[(c-166)*NN + j];
        bufA[i] = v;
    }
    __syncthreads();
    int ro = tid & 63, kb = (tid >> 6) * 5;
    const float* w2p = ws + O_W2P;
    float acc[4][5];
    #pragma unroll
    for (int j = 0; j < 4; ++j)
        #pragma unroll
        for (int kk = 0; kk < 5; ++kk) acc[j][kk] = 0.f;
    for (int c4 = 0; c4 < 64; ++c4) {
        float4 gv[5], wv[4];
        #pragma unroll
        for (int kk = 0; kk < 5; ++kk) gv[kk] = *(const float4*)&bufA[(kb+kk)*256 + c4*4];
        #pragma unroll
        for (int j = 0; j < 4; ++j) wv[j] = *(const float4*)&w2p[(ro + 64*j)*256 + c4*4];
        #pragma unroll
        for (int j = 0; j < 4; ++j)
            #pragma unroll
            for (int kk = 0; kk < 5; ++kk)
                acc[j][kk] += wv[j].x*gv[kk].x + wv[j].y*gv[kk].y + wv[j].z*gv[kk].z + wv[j].w*gv[kk].w;
    }
    __syncthreads();  // all g2T reads done before bufA is reused as attL
    #pragma unroll
    for (int j = 0; j < 4; ++j) {
        int r = ro + 64*j;
        float s2 = ws[O_BN2SC + r], h2s = ws[O_BN2SH + r];
        float ps = ws[O_P2SC + r], ph = ws[O_P2SH + r];
        #pragma unroll
        for (int kk = 0; kk < 5; ++kk) {
            float v = acc[j][kk]*s2 + h2s;
            v = v > 0.f ? v : 0.2f*v;
            h2L[r*21 + kb + kk] = v;
            float hv = v*ps + ph;
            hrT[(kb+kk)*256 + r] = hv > 0.f ? hv : 0.f;
        }
    }
    __syncthreads();
    const float* p2w = ws + O_P2W;
    float ac2[4][5];
    #pragma unroll
    for (int j = 0; j < 4; ++j)
        #pragma unroll
        for (int kk = 0; kk < 5; ++kk) ac2[j][kk] = 0.f;
    for (int c4 = 0; c4 < 64; ++c4) {
        float4 gv[5], wv[4];
        #pragma unroll
        for (int kk = 0; kk < 5; ++kk) gv[kk] = *(const float4*)&hrT[(kb+kk)*256 + c4*4];
        #pragma unroll
        for (int j = 0; j < 4; ++j) wv[j] = *(const float4*)&p2w[(ro + 64*j)*256 + c4*4];
        #pragma unroll
        for (int j = 0; j < 4; ++j)
            #pragma unroll
            for (int kk = 0; kk < 5; ++kk)
                ac2[j][kk] += wv[j].x*gv[kk].x + wv[j].y*gv[kk].y + wv[j].z*gv[kk].z + wv[j].w*gv[kk].w;
    }
    __syncthreads();   // hrT reads done before bufA overwrite below
    #pragma unroll
    for (int j = 0; j < 4; ++j) {
        int r = ro + 64*j;
        float pb = ws[O_P2B + r];
        #pragma unroll
        for (int kk = 0; kk < 5; ++kk) bufA[r*21 + kb + kk] = ac2[j][kk] + pb;   // attL
    }
    __syncthreads();
    {
        int o = tid;   // 256
        float av[KK]; float mx = -3.0e38f;
        #pragma unroll
        for (int k = 0; k < KK; ++k) { av[k] = bufA[o*21 + k]; mx = fmaxf(mx, av[k]); }
        float ssum = 0.f;
        #pragma unroll
        for (int k = 0; k < KK; ++k) { av[k] = expf(av[k] - mx); ssum += av[k]; }
        float outv = 0.f;
        #pragma unroll
        for (int k = 0; k < KK; ++k) outv += h2L[o*21 + k] * (av[k]/ssum);
        ws[O_XC2 + b*512*NN + (256+o)*NN + n] = outv;
    }
}

// ================= final: out = lrelu(bn3(w3 @ x_c2)) -> fp32 =================
__global__ void final_kernel(const float* ws, float* out) {
    __shared__ __align__(16) float tileF[512*16];
    int tid = threadIdx.x;
    int b = blockIdx.x >> 7;
    int n0 = (blockIdx.x & 127) << 4;
    const float* xc2 = ws + O_XC2 + b*512*NN;
    for (int i = tid; i < 512*16; i += 256) {
        int c = i >> 4, nn = i & 15;
        tileF[i] = xc2[c*NN + n0 + nn];
    }
    __syncthreads();
    const float* w3p = ws + O_W3P;
    int r0 = tid*2, r1 = r0 + 1;
    float acc0[16], acc1[16];
    #pragma unroll
    for (int q = 0; q < 16; ++q) { acc0[q] = 0.f; acc1[q] = 0.f; }
    #pragma unroll 4
    for (int c = 0; c < 512; ++c) {
        float w0 = w3p[r0*512 + c], w1v = w3p[r1*512 + c];
        const float4* tr = (const float4*)&tileF[c*16];
        #pragma unroll
        for (int q = 0; q < 4; ++q) {
            float4 t = tr[q];
            acc0[q*4+0] += w0*t.x;  acc0[q*4+1] += w0*t.y;  acc0[q*4+2] += w0*t.z;  acc0[q*4+3] += w0*t.w;
            acc1[q*4+0] += w1v*t.x; acc1[q*4+1] += w1v*t.y; acc1[q*4+2] += w1v*t.z; acc1[q*4+3] += w1v*t.w;
        }
    }
    float s0 = ws[O_BN3SC + r0], q0 = ws[O_BN3SH + r0];
    float s1 = ws[O_BN3SC + r1], q1 = ws[O_BN3SH + r1];
    float* ob = out + b*512*NN;
    #pragma unroll
    for (int nn = 0; nn < 16; ++nn) {
        float v = acc0[nn]*s0 + q0; v = v > 0.f ? v : 0.2f*v;
        ob[r0*NN + n0 + nn] = v;
        float u = acc1[nn]*s1 + q1; u = u > 0.f ? u : 0.2f*u;
        ob[r1*NN + n0 + nn] = u;
    }
}

extern "C" void kernel_launch(void* const* d_in, const int* in_sizes, int n_in,
                              void* d_out, int out_size, void* d_ws, size_t ws_size,
                              hipStream_t stream) {
    float* ws = (float*)d_ws;
    float* out = (float*)d_out;

    detect_kernel<<<1, 64, 0, stream>>>(d_in[0], (int*)ws + O_FLAG);
    prep_kernel<<<64, 256, 0, stream>>>(d_in[1], d_in[2], d_in[3], d_in[4], d_in[5], d_in[6],
                                        d_in[7], d_in[8], d_in[9], d_in[10], d_in[11], d_in[12],
                                        d_in[13], d_in[14], d_in[15], d_in[16], d_in[17], d_in[18],
                                        d_in[19], d_in[20], d_in[21], ws);
    lafe_kernel<<<64, 256, 0, stream>>>(d_in[0], ws);
    knn_kernel<19, 256><<<64, 256, 0, stream>>>(ws + O_XMAN, (int*)(ws + O_IDX2));
    mlp_kernel<<<BB*NN, 256, 0, stream>>>(ws);
    edge1_kernel<<<BB*NN, 64, 0, stream>>>(ws, (const int*)(ws + O_IDX2));
    knn_kernel<83, 128><<<64, 256, 0, stream>>>(ws + O_XC1, (int*)(ws + O_IDX3));
    edge2_kernel<<<BB*NN, 256, 0, stream>>>(ws, (const int*)(ws + O_IDX3));
    final_kernel<<<BB*(NN/16), 256, 0, stream>>>(ws, out);
}

// Round 5
// 8102.328 us; speedup vs baseline: 4.6470x; 4.1180x over previous
//
#include <hip/hip_runtime.h>
#include <hip/hip_bf16.h>
#include <math.h>

typedef __hip_bfloat16 bf16;

#define BB 8
#define NN 2048
#define KK 20

// ---- workspace layout (float offsets) ----
#define O_XMAN  0                        // [8][19][2048]
#define O_XC1   311296                   // [8][83][2048]
#define O_XC2   1671168                  // [8][512][2048] (rows 0..255 = x_mlp, 256..511 = xp2)
                                         // ALSO reused (before mlp/edge2 write it) as knn partial scratch
#define O_IDX2  10059776                 // int [8][2048][20]
#define O_IDX3  10387456                 // int [8][2048][20]
#define O_MLPW  10715136                 // [256][20] padded
#define O_MLPSC 10720256
#define O_MLPSH 10720512
#define O_W1P   10720768                 // [64][64] padded
#define O_BN1SC 10724864
#define O_BN1SH 10724928
#define O_P1SC  10724992
#define O_P1SH  10725056
#define O_P1W   10725120                 // [64][64]
#define O_P1B   10729216
#define O_W2P   10729280                 // [256][256] padded
#define O_BN2SC 10794816
#define O_BN2SH 10795072
#define O_P2SC  10795328
#define O_P2SH  10795584
#define O_P2W   10795840                 // [256][256]
#define O_P2B   10861376
#define O_W3P   10861632                 // [512][512]
#define O_BN3SC 11123776
#define O_BN3SH 11124288
#define O_LA    11124800                 // w1[48] b1[16] w2[48] b2[16] w3[16] b3[1]
#define O_FLAG  11124960                 // int: 1 if inputs are fp32, 0 if bf16

// knn partial scratch inside XC2 region (consumed before mlp/edge2 write XC2):
// values: [S][8][2048][20] floats; indices: same count of ints. Max S=4 -> 1.31M each.
#define O_PKV   O_XC2
#define O_PKI   (O_XC2 + 1310720)

__device__ __forceinline__ float ldin(const void* p, int i, int f32) {
    return f32 ? ((const float*)p)[i]
               : __bfloat162float(((const bf16*)p)[i]);
}

// top-k insertion with ONLY compile-time array indices; needs __launch_bounds__
// on the caller so the VGPR budget (default cap 64 = 8 waves/EU target) does not
// force tv/ti/myf into scratch (round-4: 7.8 GB scratch writes, VALUBusy 0.65%).
// jax tie semantics: strict > to displace the min; strict > to bubble past,
// so equal values keep the earlier (lower) index first.
__device__ __forceinline__ void topk_ins(float (&tv)[KK], int (&ti)[KK], float d, int m) {
    if (d > tv[KK-1]) {
        tv[KK-1] = d; ti[KK-1] = m;
        #pragma unroll
        for (int j = KK-1; j > 0; --j) {
            if (tv[j] > tv[j-1]) {
                float tf = tv[j-1]; tv[j-1] = tv[j]; tv[j] = tf;
                int   tx = ti[j-1]; ti[j-1] = ti[j]; ti[j] = tx;
            }
        }
    }
}

// ============ detect: are inputs fp32 or bf16? ============
__global__ void detect_kernel(const void* x, int* flag) {
    if (threadIdx.x == 0 && blockIdx.x == 0) {
        const unsigned short* u = (const unsigned short*)x;
        int bad = 0;
        for (int i = 0; i < 64; ++i) {
            int e = (u[i] >> 7) & 0xFF;
            if (e >= 0x86) bad++;       // |v| >= 64 or inf/nan: implausible for N(0,1) bf16
        }
        *flag = (bad > 0) ? 1 : 0;
    }
}

// ================= prep: inputs -> fp32, pad, fold BN =================
__global__ void prep_kernel(
    const void* la_w1, const void* la_b1, const void* la_w2, const void* la_b2,
    const void* la_w3, const void* la_b3,
    const void* mlp_w, const void* mlp_b, const void* mlp_bn,
    const void* w1, const void* bn1, const void* w2, const void* bn2,
    const void* w3, const void* bn3,
    const void* p1_bn, const void* p1_w, const void* p1_b,
    const void* p2_bn, const void* p2_w, const void* p2_b,
    float* ws)
{
    const int f32 = ((const int*)ws)[O_FLAG];
    int gid = blockIdx.x * blockDim.x + threadIdx.x;
    int gsz = gridDim.x * blockDim.x;

    for (int i = gid; i < 256*20; i += gsz) {
        int o = i / 20, c = i - o*20;
        ws[O_MLPW + i] = (c < 19) ? ldin(mlp_w, o*19 + c, f32) : 0.f;
    }
    for (int c = gid; c < 256; c += gsz) {
        float g = ldin(mlp_bn, c, f32), be = ldin(mlp_bn, 256+c, f32);
        float m = ldin(mlp_bn, 512+c, f32), vv = ldin(mlp_bn, 768+c, f32);
        float s = g / sqrtf(vv + 1e-5f);
        ws[O_MLPSC + c] = s;
        ws[O_MLPSH + c] = be + (ldin(mlp_b, c, f32) - m) * s;
    }
    for (int i = gid; i < 64*64; i += gsz) {
        int o = i >> 6, c = i & 63;
        ws[O_W1P + i] = (c < 57) ? ldin(w1, o*57 + c, f32) : 0.f;
    }
    for (int c = gid; c < 64; c += gsz) {
        float g = ldin(bn1, c, f32), be = ldin(bn1, 64+c, f32);
        float m = ldin(bn1, 128+c, f32), vv = ldin(bn1, 192+c, f32);
        float s = g / sqrtf(vv + 1e-5f);
        ws[O_BN1SC + c] = s; ws[O_BN1SH + c] = be - m*s;
        float g2 = ldin(p1_bn, c, f32), be2 = ldin(p1_bn, 64+c, f32);
        float m2 = ldin(p1_bn, 128+c, f32), vv2 = ldin(p1_bn, 192+c, f32);
        float s2 = g2 / sqrtf(vv2 + 1e-5f);
        ws[O_P1SC + c] = s2; ws[O_P1SH + c] = be2 - m2*s2;
        ws[O_P1B + c] = ldin(p1_b, c, f32);
    }
    for (int i = gid; i < 64*64; i += gsz) ws[O_P1W + i] = ldin(p1_w, i, f32);
    for (int i = gid; i < 256*256; i += gsz) {
        int o = i >> 8, c = i & 255;
        ws[O_W2P + i] = (c < 249) ? ldin(w2, o*249 + c, f32) : 0.f;
    }
    for (int c = gid; c < 256; c += gsz) {
        float g = ldin(bn2, c, f32), be = ldin(bn2, 256+c, f32);
        float m = ldin(bn2, 512+c, f32), vv = ldin(bn2, 768+c, f32);
        float s = g / sqrtf(vv + 1e-5f);
        ws[O_BN2SC + c] = s; ws[O_BN2SH + c] = be - m*s;
        float g2 = ldin(p2_bn, c, f32), be2 = ldin(p2_bn, 256+c, f32);
        float m2 = ldin(p2_bn, 512+c, f32), vv2 = ldin(p2_bn, 768+c, f32);
        float s2 = g2 / sqrtf(vv2 + 1e-5f);
        ws[O_P2SC + c] = s2; ws[O_P2SH + c] = be2 - m2*s2;
        ws[O_P2B + c] = ldin(p2_b, c, f32);
    }
    for (int i = gid; i < 256*256; i += gsz) ws[O_P2W + i] = ldin(p2_w, i, f32);
    for (int i = gid; i < 512*512; i += gsz) ws[O_W3P + i] = ldin(w3, i, f32);
    for (int c = gid; c < 512; c += gsz) {
        float g = ldin(bn3, c, f32), be = ldin(bn3, 512+c, f32);
        float m = ldin(bn3, 1024+c, f32), vv = ldin(bn3, 1536+c, f32);
        float s = g / sqrtf(vv + 1e-5f);
        ws[O_BN3SC + c] = s; ws[O_BN3SH + c] = be - m*s;
    }
    for (int i = gid; i < 48; i += gsz) ws[O_LA + i]       = ldin(la_w1, i, f32);
    for (int i = gid; i < 16; i += gsz) ws[O_LA + 48 + i]  = ldin(la_b1, i, f32);
    for (int i = gid; i < 48; i += gsz) ws[O_LA + 64 + i]  = ldin(la_w2, i, f32);
    for (int i = gid; i < 16; i += gsz) ws[O_LA + 112 + i] = ldin(la_b2, i, f32);
    for (int i = gid; i < 16; i += gsz) ws[O_LA + 128 + i] = ldin(la_w3, i, f32);
    if (gid == 0) ws[O_LA + 144] = ldin(la_b3, 0, f32);
}

// ================= lafe: knn(C=3) + local attention -> x_manet =================
__global__ __launch_bounds__(256, 1) void lafe_kernel(const void* x, float* ws) {
    __shared__ float xs0[NN], xs1[NN], xs2[NN], xxs[NN];
    const int f32 = ((const int*)ws)[O_FLAG];
    int tid = threadIdx.x;
    int b = blockIdx.x >> 3;
    int n = ((blockIdx.x & 7) << 8) + tid;
    int xoff = b * 3 * NN;
    for (int i = tid; i < NN; i += 256) {
        float v0 = ldin(x, xoff + i, f32);
        float v1 = ldin(x, xoff + NN + i, f32);
        float v2 = ldin(x, xoff + 2*NN + i, f32);
        xs0[i] = v0; xs1[i] = v1; xs2[i] = v2;
        xxs[i] = v0*v0 + v1*v1 + v2*v2;
    }
    __syncthreads();
    float a0 = xs0[n], a1 = xs1[n], a2 = xs2[n];
    float xxn = xxs[n];
    float tv[KK]; int ti[KK];
    #pragma unroll
    for (int k = 0; k < KK; ++k) { tv[k] = -3.0e38f; ti[k] = 0; }
    for (int m = 0; m < NN; ++m) {
        float d = 2.f*(a0*xs0[m] + a1*xs1[m] + a2*xs2[m]) - xxn - xxs[m];
        topk_ins(tv, ti, d, m);
    }
    const float* wl = ws + O_LA;
    float sa = wl[144];
    #pragma unroll
    for (int o = 0; o < 16; ++o) {
        float nf = wl[o*3+0]*a0 + wl[o*3+1]*a1 + wl[o*3+2]*a2 + wl[48+o];
        sa += wl[128+o]*nf;
    }
    float lg[KK]; float mx = -3.0e38f;
    #pragma unroll
    for (int k = 0; k < KK; ++k) {
        int m = ti[k] & (NN-1);
        float d0 = a0 - xs0[m], d1 = a1 - xs1[m], d2 = a2 - xs2[m];
        float na = wl[144];
        #pragma unroll
        for (int o = 0; o < 16; ++o) {
            float ef = wl[64+o*3+0]*d0 + wl[64+o*3+1]*d1 + wl[64+o*3+2]*d2 + wl[112+o];
            na += wl[128+o]*ef;
        }
        float t = sa + na;
        t = t > 0.f ? t : 0.01f*t;     // leaky 0.01
        lg[k] = t; mx = fmaxf(mx, t);
    }
    float ssum = 0.f;
    #pragma unroll
    for (int k = 0; k < KK; ++k) { lg[k] = expf(lg[k] - mx); ssum += lg[k]; }
    float vals[16];
    #pragma unroll
    for (int o = 0; o < 16; ++o) vals[o] = 0.f;
    #pragma unroll
    for (int k = 0; k < KK; ++k) {
        float coef = lg[k] / ssum;
        int m = ti[k] & (NN-1);
        float d0 = a0 - xs0[m], d1 = a1 - xs1[m], d2 = a2 - xs2[m];
        #pragma unroll
        for (int o = 0; o < 16; ++o) {
            float ef = wl[64+o*3+0]*d0 + wl[64+o*3+1]*d1 + wl[64+o*3+2]*d2 + wl[112+o];
            vals[o] += coef * ef;
        }
    }
    float* xm = ws + O_XMAN + b * 19 * NN;
    xm[0*NN + n] = a0; xm[1*NN + n] = a1; xm[2*NN + n] = a2;
    #pragma unroll
    for (int o = 0; o < 16; ++o) {
        float v = vals[o];
        xm[(3+o)*NN + n] = v > 0.f ? v : expm1f(v);   // elu
    }
}

// ====== knn partial: each block scans m-range s of S, keeps top-20 ======
// grid: 8(b) x 8(n-chunk) x S ; blockIdx.x = ((b*8 + chunk)*S + s)
template<int C, int TILE, int S>
__global__ __launch_bounds__(256, 1) void knn_part_kernel(const float* feat, float* pv, int* pi) {
    __shared__ __align__(16) float tile[C * TILE + TILE];   // + xx at the end
    float* xxt = tile + C * TILE;
    int tid = threadIdx.x;
    int s = blockIdx.x & (S-1);
    int bc = blockIdx.x / S;
    int b = bc >> 3;
    int n = ((bc & 7) << 8) + tid;
    const float* fb = feat + b * C * NN;
    float myf[C];
    #pragma unroll
    for (int c = 0; c < C; ++c) myf[c] = fb[c*NN + n];
    float xxn = 0.f;
    #pragma unroll
    for (int c = 0; c < C; ++c) xxn += myf[c]*myf[c];
    float tv[KK]; int ti[KK];
    #pragma unroll
    for (int k = 0; k < KK; ++k) { tv[k] = -3.0e38f; ti[k] = 0; }
    const int T0 = s * (NN / S / TILE), T1 = (s+1) * (NN / S / TILE);
    for (int t = T0; t < T1; ++t) {
        __syncthreads();
        for (int i = tid; i < C*TILE; i += 256) {
            int c = i / TILE, j = i - c*TILE;
            tile[i] = fb[c*NN + t*TILE + j];
        }
        __syncthreads();
        for (int j = tid; j < TILE; j += 256) {
            float sq = 0.f;
            #pragma unroll
            for (int c = 0; c < C; ++c) sq += tile[c*TILE + j]*tile[c*TILE + j];
            xxt[j] = sq;
        }
        __syncthreads();
        for (int j4 = 0; j4 < TILE/4; ++j4) {
            float4 dot = make_float4(0.f, 0.f, 0.f, 0.f);
            #pragma unroll
            for (int c = 0; c < C; ++c) {
                float4 tvv = *(const float4*)&tile[c*TILE + j4*4];
                float f = myf[c];
                dot.x += f*tvv.x; dot.y += f*tvv.y; dot.z += f*tvv.z; dot.w += f*tvv.w;
            }
            float4 xxv = *(const float4*)&xxt[j4*4];
            int mb = t*TILE + j4*4;
            topk_ins(tv, ti, 2.f*dot.x - xxn - xxv.x, mb+0);
            topk_ins(tv, ti, 2.f*dot.y - xxn - xxv.y, mb+1);
            topk_ins(tv, ti, 2.f*dot.z - xxn - xxv.z, mb+2);
            topk_ins(tv, ti, 2.f*dot.w - xxn - xxv.w, mb+3);
        }
    }
    long base = ((long)(s*BB + b)*NN + n)*KK;
    #pragma unroll
    for (int k = 0; k < KK; ++k) { pv[base + k] = tv[k]; pi[base + k] = ti[k]; }
}

// ====== knn merge: combine S sorted partial lists (ascending m-range) ======
template<int S>
__global__ __launch_bounds__(256, 1) void knn_merge_kernel(const float* pv, const int* pi, int* idxout) {
    int gid = blockIdx.x*256 + threadIdx.x;   // = b*NN + n, 16384 total
    float tv[KK]; int ti[KK];
    #pragma unroll
    for (int k = 0; k < KK; ++k) { tv[k] = -3.0e38f; ti[k] = 0; }
    #pragma unroll
    for (int s = 0; s < S; ++s) {
        long base = ((long)s*BB*NN + gid)*KK;
        #pragma unroll
        for (int k = 0; k < KK; ++k)
            topk_ins(tv, ti, pv[base + k], pi[base + k]);
    }
    #pragma unroll
    for (int k = 0; k < KK; ++k) idxout[(long)gid*KK + k] = ti[k];
}

// ================= mlp: x_mlp = relu(bn(W @ x_manet + b)) -> xc2 rows 0..255 =================
__global__ void mlp_kernel(float* ws) {
    __shared__ __align__(16) float xv[20];
    int tid = threadIdx.x;
    int b = blockIdx.x >> 11, n = blockIdx.x & 2047;
    if (tid < 20) xv[tid] = (tid < 19) ? ws[O_XMAN + b*19*NN + tid*NN + n] : 0.f;
    __syncthreads();
    const float* mw = ws + O_MLPW;
    float acc = 0.f;
    #pragma unroll
    for (int c4 = 0; c4 < 5; ++c4) {
        float4 w = *(const float4*)&mw[tid*20 + c4*4];
        float4 g = *(const float4*)&xv[c4*4];
        acc += w.x*g.x + w.y*g.y + w.z*g.z + w.w*g.w;
    }
    float v = acc * ws[O_MLPSC + tid] + ws[O_MLPSH + tid];
    ws[O_XC2 + b*512*NN + tid*NN + n] = fmaxf(v, 0.f);
}

// ================= edge1: h1 = lrelu(bn1(w1 @ g1)), att-pool p1 -> xc1 =================
__global__ void edge1_kernel(float* ws, const int* idx) {
    __shared__ __align__(16) float g1T[KK*64];
    __shared__ __align__(16) float h1L[64*21];
    __shared__ __align__(16) float hrT[KK*64];
    __shared__ __align__(16) float attL[64*21];
    __shared__ float xcL[19];
    __shared__ int idxL[KK];
    int tid = threadIdx.x;
    int b = blockIdx.x >> 11, n = blockIdx.x & 2047;
    const float* xb = ws + O_XMAN + b*19*NN;
    if (tid < KK) idxL[tid] = idx[(b*NN + n)*KK + tid] & (NN-1);
    if (tid < 19) xcL[tid] = xb[tid*NN + n];
    __syncthreads();
    for (int i = tid; i < KK*64; i += 64) {
        int k = i >> 6, c = i & 63;
        int j = idxL[k];
        float v = 0.f;
        if (c < 19) v = xb[c*NN + j];
        else if (c < 38) v = xcL[c-19];
        else if (c < 57) v = xcL[c-38] - xb[(c-38)*NN + j];
        g1T[i] = v;
    }
    __syncthreads();
    int ro = tid & 15, kb = (tid >> 4) * 5;
    const float* w1p = ws + O_W1P;
    float acc[4][5];
    #pragma unroll
    for (int j = 0; j < 4; ++j)
        #pragma unroll
        for (int kk = 0; kk < 5; ++kk) acc[j][kk] = 0.f;
    for (int c4 = 0; c4 < 16; ++c4) {
        float4 gv[5], wv[4];
        #pragma unroll
        for (int kk = 0; kk < 5; ++kk) gv[kk] = *(const float4*)&g1T[(kb+kk)*64 + c4*4];
        #pragma unroll
        for (int j = 0; j < 4; ++j) wv[j] = *(const float4*)&w1p[(ro + 16*j)*64 + c4*4];
        #pragma unroll
        for (int j = 0; j < 4; ++j)
            #pragma unroll
            for (int kk = 0; kk < 5; ++kk)
                acc[j][kk] += wv[j].x*gv[kk].x + wv[j].y*gv[kk].y + wv[j].z*gv[kk].z + wv[j].w*gv[kk].w;
    }
    #pragma unroll
    for (int j = 0; j < 4; ++j) {
        int r = ro + 16*j;
        float s1 = ws[O_BN1SC + r], h1s = ws[O_BN1SH + r];
        float ps = ws[O_P1SC + r], ph = ws[O_P1SH + r];
        #pragma unroll
        for (int kk = 0; kk < 5; ++kk) {
            float v = acc[j][kk]*s1 + h1s;
            v = v > 0.f ? v : 0.2f*v;
            h1L[r*21 + kb + kk] = v;
            float hv = v*ps + ph;
            hrT[(kb+kk)*64 + r] = hv > 0.f ? hv : 0.f;
        }
    }
    __syncthreads();
    const float* p1w = ws + O_P1W;
    float ac2[4][5];
    #pragma unroll
    for (int j = 0; j < 4; ++j)
        #pragma unroll
        for (int kk = 0; kk < 5; ++kk) ac2[j][kk] = 0.f;
    for (int c4 = 0; c4 < 16; ++c4) {
        float4 gv[5], wv[4];
        #pragma unroll
        for (int kk = 0; kk < 5; ++kk) gv[kk] = *(const float4*)&hrT[(kb+kk)*64 + c4*4];
        #pragma unroll
        for (int j = 0; j < 4; ++j) wv[j] = *(const float4*)&p1w[(ro + 16*j)*64 + c4*4];
        #pragma unroll
        for (int j = 0; j < 4; ++j)
            #pragma unroll
            for (int kk = 0; kk < 5; ++kk)
                ac2[j][kk] += wv[j].x*gv[kk].x + wv[j].y*gv[kk].y + wv[j].z*gv[kk].z + wv[j].w*gv[kk].w;
    }
    #pragma unroll
    for (int j = 0; j < 4; ++j) {
        int r = ro + 16*j;
        float pb = ws[O_P1B + r];
        #pragma unroll
        for (int kk = 0; kk < 5; ++kk) attL[r*21 + kb + kk] = ac2[j][kk] + pb;
    }
    __syncthreads();
    {
        int o = tid;   // 64 threads
        float av[KK]; float mx = -3.0e38f;
        #pragma unroll
        for (int k = 0; k < KK; ++k) { av[k] = attL[o*21 + k]; mx = fmaxf(mx, av[k]); }
        float ssum = 0.f;
        #pragma unroll
        for (int k = 0; k < KK; ++k) { av[k] = expf(av[k] - mx); ssum += av[k]; }
        float outv = 0.f;
        #pragma unroll
        for (int k = 0; k < KK; ++k) outv += h1L[o*21 + k] * (av[k]/ssum);
        float* xc1 = ws + O_XC1 + b*83*NN;
        xc1[(19+o)*NN + n] = outv;
        if (tid < 19) xc1[tid*NN + n] = xcL[tid];
    }
}

// ================= edge2: h2 = lrelu(bn2(w2 @ g2)), att-pool p2 -> xc2 rows 256..511 =================
__global__ void edge2_kernel(float* ws, const int* idx) {
    __shared__ __align__(16) float bufA[5376];      // g2T [20][256] then attL [256][21]
    __shared__ __align__(16) float h2L[256*21];
    __shared__ __align__(16) float hrT[KK*256];
    __shared__ float xcL[83];
    __shared__ int idxL[KK];
    int tid = threadIdx.x;
    int b = blockIdx.x >> 11, n = blockIdx.x & 2047;
    const float* xb = ws + O_XC1 + b*83*NN;
    if (tid < KK) idxL[tid] = idx[(b*NN + n)*KK + tid] & (NN-1);
    if (tid < 83) xcL[tid] = xb[tid*NN + n];
    __syncthreads();
    for (int i = tid; i < KK*256; i += 256) {
        int k = i >> 8, c = i & 255;
        int j = idxL[k];
        float v = 0.f;
        if (c < 83) v = xb[c*NN + j];
        else if (c < 166) v = xcL[c-83];
        else if (c < 249) v = xcL[c-166] - xb[(c-166)*NN + j];
        bufA[i] = v;
    }
    __syncthreads();
    int ro = tid & 63, kb = (tid >> 6) * 5;
    const float* w2p = ws + O_W2P;
    float acc[4][5];
    #pragma unroll
    for (int j = 0; j < 4; ++j)
        #pragma unroll
        for (int kk = 0; kk < 5; ++kk) acc[j][kk] = 0.f;
    for (int c4 = 0; c4 < 64; ++c4) {
        float4 gv[5], wv[4];
        #pragma unroll
        for (int kk = 0; kk < 5; ++kk) gv[kk] = *(const float4*)&bufA[(kb+kk)*256 + c4*4];
        #pragma unroll
        for (int j = 0; j < 4; ++j) wv[j] = *(const float4*)&w2p[(ro + 64*j)*256 + c4*4];
        #pragma unroll
        for (int j = 0; j < 4; ++j)
            #pragma unroll
            for (int kk = 0; kk < 5; ++kk)
                acc[j][kk] += wv[j].x*gv[kk].x + wv[j].y*gv[kk].y + wv[j].z*gv[kk].z + wv[j].w*gv[kk].w;
    }
    __syncthreads();  // all g2T reads done before bufA is reused as attL
    #pragma unroll
    for (int j = 0; j < 4; ++j) {
        int r = ro + 64*j;
        float s2 = ws[O_BN2SC + r], h2s = ws[O_BN2SH + r];
        float ps = ws[O_P2SC + r], ph = ws[O_P2SH + r];
        #pragma unroll
        for (int kk = 0; kk < 5; ++kk) {
            float v = acc[j][kk]*s2 + h2s;
            v = v > 0.f ? v : 0.2f*v;
            h2L[r*21 + kb + kk] = v;
            float hv = v*ps + ph;
            hrT[(kb+kk)*256 + r] = hv > 0.f ? hv : 0.f;
        }
    }
    __syncthreads();
    const float* p2w = ws + O_P2W;
    float ac2[4][5];
    #pragma unroll
    for (int j = 0; j < 4; ++j)
        #pragma unroll
        for (int kk = 0; kk < 5; ++kk) ac2[j][kk] = 0.f;
    for (int c4 = 0; c4 < 64; ++c4) {
        float4 gv[5], wv[4];
        #pragma unroll
        for (int kk = 0; kk < 5; ++kk) gv[kk] = *(const float4*)&hrT[(kb+kk)*256 + c4*4];
        #pragma unroll
        for (int j = 0; j < 4; ++j) wv[j] = *(const float4*)&p2w[(ro + 64*j)*256 + c4*4];
        #pragma unroll
        for (int j = 0; j < 4; ++j)
            #pragma unroll
            for (int kk = 0; kk < 5; ++kk)
                ac2[j][kk] += wv[j].x*gv[kk].x + wv[j].y*gv[kk].y + wv[j].z*gv[kk].z + wv[j].w*gv[kk].w;
    }
    __syncthreads();   // hrT reads done before bufA overwrite below
    #pragma unroll
    for (int j = 0; j < 4; ++j) {
        int r = ro + 64*j;
        float pb = ws[O_P2B + r];
        #pragma unroll
        for (int kk = 0; kk < 5; ++kk) bufA[r*21 + kb + kk] = ac2[j][kk] + pb;   // attL
    }
    __syncthreads();
    {
        int o = tid;   // 256
        float av[KK]; float mx = -3.0e38f;
        #pragma unroll
        for (int k = 0; k < KK; ++k) { av[k] = bufA[o*21 + k]; mx = fmaxf(mx, av[k]); }
        float ssum = 0.f;
        #pragma unroll
        for (int k = 0; k < KK; ++k) { av[k] = expf(av[k] - mx); ssum += av[k]; }
        float outv = 0.f;
        #pragma unroll
        for (int k = 0; k < KK; ++k) outv += h2L[o*21 + k] * (av[k]/ssum);
        ws[O_XC2 + b*512*NN + (256+o)*NN + n] = outv;
    }
}

// ================= final: out = lrelu(bn3(w3 @ x_c2)) -> fp32 =================
__global__ void final_kernel(const float* ws, float* out) {
    __shared__ __align__(16) float tileF[512*16];
    int tid = threadIdx.x;
    int b = blockIdx.x >> 7;
    int n0 = (blockIdx.x & 127) << 4;
    const float* xc2 = ws + O_XC2 + b*512*NN;
    for (int i = tid; i < 512*16; i += 256) {
        int c = i >> 4, nn = i & 15;
        tileF[i] = xc2[c*NN + n0 + nn];
    }
    __syncthreads();
    const float* w3p = ws + O_W3P;
    int r0 = tid*2, r1 = r0 + 1;
    float acc0[16], acc1[16];
    #pragma unroll
    for (int q = 0; q < 16; ++q) { acc0[q] = 0.f; acc1[q] = 0.f; }
    #pragma unroll 4
    for (int c = 0; c < 512; ++c) {
        float w0 = w3p[r0*512 + c], w1v = w3p[r1*512 + c];
        const float4* tr = (const float4*)&tileF[c*16];
        #pragma unroll
        for (int q = 0; q < 4; ++q) {
            float4 t = tr[q];
            acc0[q*4+0] += w0*t.x;  acc0[q*4+1] += w0*t.y;  acc0[q*4+2] += w0*t.z;  acc0[q*4+3] += w0*t.w;
            acc1[q*4+0] += w1v*t.x; acc1[q*4+1] += w1v*t.y; acc1[q*4+2] += w1v*t.z; acc1[q*4+3] += w1v*t.w;
        }
    }
    float s0 = ws[O_BN3SC + r0], q0 = ws[O_BN3SH + r0];
    float s1 = ws[O_BN3SC + r1], q1 = ws[O_BN3SH + r1];
    float* ob = out + b*512*NN;
    #pragma unroll
    for (int nn = 0; nn < 16; ++nn) {
        float v = acc0[nn]*s0 + q0; v = v > 0.f ? v : 0.2f*v;
        ob[r0*NN + n0 + nn] = v;
        float u = acc1[nn]*s1 + q1; u = u > 0.f ? u : 0.2f*u;
        ob[r1*NN + n0 + nn] = u;
    }
}

extern "C" void kernel_launch(void* const* d_in, const int* in_sizes, int n_in,
                              void* d_out, int out_size, void* d_ws, size_t ws_size,
                              hipStream_t stream) {
    float* ws = (float*)d_ws;
    float* out = (float*)d_out;
    float* pkv = ws + O_PKV;
    int*   pki = (int*)(ws + O_PKI);

    detect_kernel<<<1, 64, 0, stream>>>(d_in[0], (int*)ws + O_FLAG);
    prep_kernel<<<64, 256, 0, stream>>>(d_in[1], d_in[2], d_in[3], d_in[4], d_in[5], d_in[6],
                                        d_in[7], d_in[8], d_in[9], d_in[10], d_in[11], d_in[12],
                                        d_in[13], d_in[14], d_in[15], d_in[16], d_in[17], d_in[18],
                                        d_in[19], d_in[20], d_in[21], ws);
    lafe_kernel<<<64, 256, 0, stream>>>(d_in[0], ws);
    // knn on x_manet (C=19), split 2 ways over candidates; partials in XC2 scratch
    knn_part_kernel<19, 256, 2><<<128, 256, 0, stream>>>(ws + O_XMAN, pkv, pki);
    knn_merge_kernel<2><<<64, 256, 0, stream>>>(pkv, pki, (int*)(ws + O_IDX2));
    edge1_kernel<<<BB*NN, 64, 0, stream>>>(ws, (const int*)(ws + O_IDX2));
    // knn on x_c1 (C=83), split 4 ways
    knn_part_kernel<83, 128, 4><<<256, 256, 0, stream>>>(ws + O_XC1, pkv, pki);
    knn_merge_kernel<4><<<64, 256, 0, stream>>>(pkv, pki, (int*)(ws + O_IDX3));
    // mlp + edge2 write XC2 (after knn scratch is consumed)
    mlp_kernel<<<BB*NN, 256, 0, stream>>>(ws);
    edge2_kernel<<<BB*NN, 256, 0, stream>>>(ws, (const int*)(ws + O_IDX3));
    final_kernel<<<BB*(NN/16), 256, 0, stream>>>(ws, out);
}

// Round 6
// 3040.348 us; speedup vs baseline: 12.3839x; 2.6649x over previous
//
#include <hip/hip_runtime.h>
#include <hip/hip_bf16.h>
#include <math.h>

typedef __hip_bfloat16 bf16;
typedef unsigned short ushort16_t;
typedef unsigned int uint32;
typedef __attribute__((ext_vector_type(8))) short short8;
typedef __attribute__((ext_vector_type(4))) float floatx4;

#define BB 8
#define NN 2048
#define KK 20

// ---- workspace layout (float offsets) ----
#define O_XMAN  0                        // [8][19][2048]
#define O_XC1   311296                   // [8][83][2048]
#define O_XC2   1671168                  // [8][512][2048] rows 0..255=x_mlp, 256..511=xp2
                                         // reused: knn partial scratch, then xc1T[b][2048][84] at start of each b-block
#define O_IDX2  10059776                 // int [8][2048][20]
#define O_IDX3  10387456                 // int [8][2048][20]
#define O_MLPW  10715136                 // [256][20] padded
#define O_MLPSC 10720256
#define O_MLPSH 10720512
#define O_W1P   10720768                 // [64][64] padded
#define O_BN1SC 10724864
#define O_BN1SH 10724928
#define O_P1SC  10724992
#define O_P1SH  10725056
#define O_P1W   10725120                 // [64][64]
#define O_P1B   10729216
#define O_W2P   10729280                 // [256][256] padded fp32 (kept for fallback/unused rows)
#define O_BN2SC 10794816
#define O_BN2SH 10795072
#define O_P2SC  10795328
#define O_P2SH  10795584
#define O_P2W   10795840                 // [256][256] fp32
#define O_P2B   10861376
#define O_W3P   10861632                 // [512][512]
#define O_BN3SC 11123776
#define O_BN3SH 11124288
#define O_LA    11124800                 // w1[48] b1[16] w2[48] b2[16] w3[16] b3[1]
#define O_FLAG  11124960                 // int: 1 if inputs are fp32, 0 if bf16
#define O_W2B16 11125760                 // ushort [256][288] bf16 w2, segment-padded (36864 floats)
#define O_P2W16 11162624                 // ushort [256][256] bf16 p2w (32768 floats)

// knn partial scratch inside XC2 region (consumed before xpose/mlp/edge2 write XC2)
#define O_PKV   O_XC2
#define O_PKI   (O_XC2 + 1310720)

__device__ __forceinline__ float ldin(const void* p, int i, int f32) {
    return f32 ? ((const float*)p)[i]
               : __bfloat162float(((const bf16*)p)[i]);
}

__device__ __forceinline__ ushort16_t f2bf(float v) {
    union { bf16 h; ushort16_t u; } x; x.h = __float2bfloat16(v); return x.u;
}

__device__ __forceinline__ void st4bf(ushort16_t* p, float a, float b, float c, float d) {
    uint2 v;
    v.x = (uint32)f2bf(a) | ((uint32)f2bf(b) << 16);
    v.y = (uint32)f2bf(c) | ((uint32)f2bf(d) << 16);
    *(uint2*)p = v;
}

// top-k insertion, compile-time indices only (VGPR-resident with __launch_bounds__)
__device__ __forceinline__ void topk_ins(float (&tv)[KK], int (&ti)[KK], float d, int m) {
    if (d > tv[KK-1]) {
        tv[KK-1] = d; ti[KK-1] = m;
        #pragma unroll
        for (int j = KK-1; j > 0; --j) {
            if (tv[j] > tv[j-1]) {
                float tf = tv[j-1]; tv[j-1] = tv[j]; tv[j] = tf;
                int   tx = ti[j-1]; ti[j-1] = ti[j]; ti[j] = tx;
            }
        }
    }
}

// ============ detect: are inputs fp32 or bf16? ============
__global__ void detect_kernel(const void* x, int* flag) {
    if (threadIdx.x == 0 && blockIdx.x == 0) {
        const unsigned short* u = (const unsigned short*)x;
        int bad = 0;
        for (int i = 0; i < 64; ++i) {
            int e = (u[i] >> 7) & 0xFF;
            if (e >= 0x86) bad++;
        }
        *flag = (bad > 0) ? 1 : 0;
    }
}

// ================= prep: inputs -> fp32, pad, fold BN, build bf16 weights =================
__global__ void prep_kernel(
    const void* la_w1, const void* la_b1, const void* la_w2, const void* la_b2,
    const void* la_w3, const void* la_b3,
    const void* mlp_w, const void* mlp_b, const void* mlp_bn,
    const void* w1, const void* bn1, const void* w2, const void* bn2,
    const void* w3, const void* bn3,
    const void* p1_bn, const void* p1_w, const void* p1_b,
    const void* p2_bn, const void* p2_w, const void* p2_b,
    float* ws)
{
    const int f32 = ((const int*)ws)[O_FLAG];
    int gid = blockIdx.x * blockDim.x + threadIdx.x;
    int gsz = gridDim.x * blockDim.x;

    for (int i = gid; i < 256*20; i += gsz) {
        int o = i / 20, c = i - o*20;
        ws[O_MLPW + i] = (c < 19) ? ldin(mlp_w, o*19 + c, f32) : 0.f;
    }
    for (int c = gid; c < 256; c += gsz) {
        float g = ldin(mlp_bn, c, f32), be = ldin(mlp_bn, 256+c, f32);
        float m = ldin(mlp_bn, 512+c, f32), vv = ldin(mlp_bn, 768+c, f32);
        float s = g / sqrtf(vv + 1e-5f);
        ws[O_MLPSC + c] = s;
        ws[O_MLPSH + c] = be + (ldin(mlp_b, c, f32) - m) * s;
    }
    for (int i = gid; i < 64*64; i += gsz) {
        int o = i >> 6, c = i & 63;
        ws[O_W1P + i] = (c < 57) ? ldin(w1, o*57 + c, f32) : 0.f;
    }
    for (int c = gid; c < 64; c += gsz) {
        float g = ldin(bn1, c, f32), be = ldin(bn1, 64+c, f32);
        float m = ldin(bn1, 128+c, f32), vv = ldin(bn1, 192+c, f32);
        float s = g / sqrtf(vv + 1e-5f);
        ws[O_BN1SC + c] = s; ws[O_BN1SH + c] = be - m*s;
        float g2 = ldin(p1_bn, c, f32), be2 = ldin(p1_bn, 64+c, f32);
        float m2 = ldin(p1_bn, 128+c, f32), vv2 = ldin(p1_bn, 192+c, f32);
        float s2 = g2 / sqrtf(vv2 + 1e-5f);
        ws[O_P1SC + c] = s2; ws[O_P1SH + c] = be2 - m2*s2;
        ws[O_P1B + c] = ldin(p1_b, c, f32);
    }
    for (int i = gid; i < 64*64; i += gsz) ws[O_P1W + i] = ldin(p1_w, i, f32);
    for (int i = gid; i < 256*256; i += gsz) {
        int o = i >> 8, c = i & 255;
        ws[O_W2P + i] = (c < 249) ? ldin(w2, o*249 + c, f32) : 0.f;
    }
    for (int c = gid; c < 256; c += gsz) {
        float g = ldin(bn2, c, f32), be = ldin(bn2, 256+c, f32);
        float m = ldin(bn2, 512+c, f32), vv = ldin(bn2, 768+c, f32);
        float s = g / sqrtf(vv + 1e-5f);
        ws[O_BN2SC + c] = s; ws[O_BN2SH + c] = be - m*s;
        float g2 = ldin(p2_bn, c, f32), be2 = ldin(p2_bn, 256+c, f32);
        float m2 = ldin(p2_bn, 512+c, f32), vv2 = ldin(p2_bn, 768+c, f32);
        float s2 = g2 / sqrtf(vv2 + 1e-5f);
        ws[O_P2SC + c] = s2; ws[O_P2SH + c] = be2 - m2*s2;
        ws[O_P2B + c] = ldin(p2_b, c, f32);
    }
    for (int i = gid; i < 256*256; i += gsz) ws[O_P2W + i] = ldin(p2_w, i, f32);
    for (int i = gid; i < 512*512; i += gsz) ws[O_W3P + i] = ldin(w3, i, f32);
    for (int c = gid; c < 512; c += gsz) {
        float g = ldin(bn3, c, f32), be = ldin(bn3, 512+c, f32);
        float m = ldin(bn3, 1024+c, f32), vv = ldin(bn3, 1536+c, f32);
        float s = g / sqrtf(vv + 1e-5f);
        ws[O_BN3SC + c] = s; ws[O_BN3SH + c] = be - m*s;
    }
    for (int i = gid; i < 48; i += gsz) ws[O_LA + i]       = ldin(la_w1, i, f32);
    for (int i = gid; i < 16; i += gsz) ws[O_LA + 48 + i]  = ldin(la_b1, i, f32);
    for (int i = gid; i < 48; i += gsz) ws[O_LA + 64 + i]  = ldin(la_w2, i, f32);
    for (int i = gid; i < 16; i += gsz) ws[O_LA + 112 + i] = ldin(la_b2, i, f32);
    for (int i = gid; i < 16; i += gsz) ws[O_LA + 128 + i] = ldin(la_w3, i, f32);
    if (gid == 0) ws[O_LA + 144] = ldin(la_b3, 0, f32);

    // bf16 weights for edge2 MFMA
    // w2b: [256][288], columns segment-padded: c' = s*88 + cc, s=0..2, cc=0..82 maps to
    // original col s*83+cc; all other c' zero. K padded 264->288 (mult of 32).
    ushort16_t* w2b = (ushort16_t*)(ws + O_W2B16);
    for (int i = gid; i < 256*288; i += gsz) {
        int row = i / 288, cp = i - row*288;
        int s = cp / 88, cc = cp - s*88;
        float v = (s < 3 && cc < 83) ? ldin(w2, row*249 + s*83 + cc, f32) : 0.f;
        w2b[i] = f2bf(v);
    }
    ushort16_t* pwb = (ushort16_t*)(ws + O_P2W16);
    for (int i = gid; i < 256*256; i += gsz) pwb[i] = f2bf(ldin(p2_w, i, f32));
}

// ================= lafe: knn(C=3) + local attention -> x_manet =================
__global__ __launch_bounds__(256, 1) void lafe_kernel(const void* x, float* ws) {
    __shared__ float xs0[NN], xs1[NN], xs2[NN], xxs[NN];
    const int f32 = ((const int*)ws)[O_FLAG];
    int tid = threadIdx.x;
    int b = blockIdx.x >> 3;
    int n = ((blockIdx.x & 7) << 8) + tid;
    int xoff = b * 3 * NN;
    for (int i = tid; i < NN; i += 256) {
        float v0 = ldin(x, xoff + i, f32);
        float v1 = ldin(x, xoff + NN + i, f32);
        float v2 = ldin(x, xoff + 2*NN + i, f32);
        xs0[i] = v0; xs1[i] = v1; xs2[i] = v2;
        xxs[i] = v0*v0 + v1*v1 + v2*v2;
    }
    __syncthreads();
    float a0 = xs0[n], a1 = xs1[n], a2 = xs2[n];
    float xxn = xxs[n];
    float tv[KK]; int ti[KK];
    #pragma unroll
    for (int k = 0; k < KK; ++k) { tv[k] = -3.0e38f; ti[k] = 0; }
    for (int m = 0; m < NN; ++m) {
        float d = 2.f*(a0*xs0[m] + a1*xs1[m] + a2*xs2[m]) - xxn - xxs[m];
        topk_ins(tv, ti, d, m);
    }
    const float* wl = ws + O_LA;
    float sa = wl[144];
    #pragma unroll
    for (int o = 0; o < 16; ++o) {
        float nf = wl[o*3+0]*a0 + wl[o*3+1]*a1 + wl[o*3+2]*a2 + wl[48+o];
        sa += wl[128+o]*nf;
    }
    float lg[KK]; float mx = -3.0e38f;
    #pragma unroll
    for (int k = 0; k < KK; ++k) {
        int m = ti[k] & (NN-1);
        float d0 = a0 - xs0[m], d1 = a1 - xs1[m], d2 = a2 - xs2[m];
        float na = wl[144];
        #pragma unroll
        for (int o = 0; o < 16; ++o) {
            float ef = wl[64+o*3+0]*d0 + wl[64+o*3+1]*d1 + wl[64+o*3+2]*d2 + wl[112+o];
            na += wl[128+o]*ef;
        }
        float t = sa + na;
        t = t > 0.f ? t : 0.01f*t;
        lg[k] = t; mx = fmaxf(mx, t);
    }
    float ssum = 0.f;
    #pragma unroll
    for (int k = 0; k < KK; ++k) { lg[k] = expf(lg[k] - mx); ssum += lg[k]; }
    float vals[16];
    #pragma unroll
    for (int o = 0; o < 16; ++o) vals[o] = 0.f;
    #pragma unroll
    for (int k = 0; k < KK; ++k) {
        float coef = lg[k] / ssum;
        int m = ti[k] & (NN-1);
        float d0 = a0 - xs0[m], d1 = a1 - xs1[m], d2 = a2 - xs2[m];
        #pragma unroll
        for (int o = 0; o < 16; ++o) {
            float ef = wl[64+o*3+0]*d0 + wl[64+o*3+1]*d1 + wl[64+o*3+2]*d2 + wl[112+o];
            vals[o] += coef * ef;
        }
    }
    float* xm = ws + O_XMAN + b * 19 * NN;
    xm[0*NN + n] = a0; xm[1*NN + n] = a1; xm[2*NN + n] = a2;
    #pragma unroll
    for (int o = 0; o < 16; ++o) {
        float v = vals[o];
        xm[(3+o)*NN + n] = v > 0.f ? v : expm1f(v);
    }
}

// ====== knn partial ======
template<int C, int TILE, int S>
__global__ __launch_bounds__(256, 1) void knn_part_kernel(const float* feat, float* pv, int* pi) {
    __shared__ __align__(16) float tile[C * TILE + TILE];
    float* xxt = tile + C * TILE;
    int tid = threadIdx.x;
    int s = blockIdx.x & (S-1);
    int bc = blockIdx.x / S;
    int b = bc >> 3;
    int n = ((bc & 7) << 8) + tid;
    const float* fb = feat + b * C * NN;
    float myf[C];
    #pragma unroll
    for (int c = 0; c < C; ++c) myf[c] = fb[c*NN + n];
    float xxn = 0.f;
    #pragma unroll
    for (int c = 0; c < C; ++c) xxn += myf[c]*myf[c];
    float tv[KK]; int ti[KK];
    #pragma unroll
    for (int k = 0; k < KK; ++k) { tv[k] = -3.0e38f; ti[k] = 0; }
    const int T0 = s * (NN / S / TILE), T1 = (s+1) * (NN / S / TILE);
    for (int t = T0; t < T1; ++t) {
        __syncthreads();
        for (int i = tid; i < C*TILE; i += 256) {
            int c = i / TILE, j = i - c*TILE;
            tile[i] = fb[c*NN + t*TILE + j];
        }
        __syncthreads();
        for (int j = tid; j < TILE; j += 256) {
            float sq = 0.f;
            #pragma unroll
            for (int c = 0; c < C; ++c) sq += tile[c*TILE + j]*tile[c*TILE + j];
            xxt[j] = sq;
        }
        __syncthreads();
        for (int j4 = 0; j4 < TILE/4; ++j4) {
            float4 dot = make_float4(0.f, 0.f, 0.f, 0.f);
            #pragma unroll
            for (int c = 0; c < C; ++c) {
                float4 tvv = *(const float4*)&tile[c*TILE + j4*4];
                float f = myf[c];
                dot.x += f*tvv.x; dot.y += f*tvv.y; dot.z += f*tvv.z; dot.w += f*tvv.w;
            }
            float4 xxv = *(const float4*)&xxt[j4*4];
            int mb = t*TILE + j4*4;
            topk_ins(tv, ti, 2.f*dot.x - xxn - xxv.x, mb+0);
            topk_ins(tv, ti, 2.f*dot.y - xxn - xxv.y, mb+1);
            topk_ins(tv, ti, 2.f*dot.z - xxn - xxv.z, mb+2);
            topk_ins(tv, ti, 2.f*dot.w - xxn - xxv.w, mb+3);
        }
    }
    long base = ((long)(s*BB + b)*NN + n)*KK;
    #pragma unroll
    for (int k = 0; k < KK; ++k) { pv[base + k] = tv[k]; pi[base + k] = ti[k]; }
}

template<int S>
__global__ __launch_bounds__(256, 1) void knn_merge_kernel(const float* pv, const int* pi, int* idxout) {
    int gid = blockIdx.x*256 + threadIdx.x;
    float tv[KK]; int ti[KK];
    #pragma unroll
    for (int k = 0; k < KK; ++k) { tv[k] = -3.0e38f; ti[k] = 0; }
    #pragma unroll
    for (int s = 0; s < S; ++s) {
        long base = ((long)s*BB*NN + gid)*KK;
        #pragma unroll
        for (int k = 0; k < KK; ++k)
            topk_ins(tv, ti, pv[base + k], pi[base + k]);
    }
    #pragma unroll
    for (int k = 0; k < KK; ++k) idxout[(long)gid*KK + k] = ti[k];
}

// ================= mlp (runs AFTER edge2 now) =================
__global__ void mlp_kernel(float* ws) {
    __shared__ __align__(16) float xv[20];
    int tid = threadIdx.x;
    int b = blockIdx.x >> 11, n = blockIdx.x & 2047;
    if (tid < 20) xv[tid] = (tid < 19) ? ws[O_XMAN + b*19*NN + tid*NN + n] : 0.f;
    __syncthreads();
    const float* mw = ws + O_MLPW;
    float acc = 0.f;
    #pragma unroll
    for (int c4 = 0; c4 < 5; ++c4) {
        float4 w = *(const float4*)&mw[tid*20 + c4*4];
        float4 g = *(const float4*)&xv[c4*4];
        acc += w.x*g.x + w.y*g.y + w.z*g.z + w.w*g.w;
    }
    float v = acc * ws[O_MLPSC + tid] + ws[O_MLPSH + tid];
    ws[O_XC2 + b*512*NN + tid*NN + n] = fmaxf(v, 0.f);
}

// ================= edge1 (unchanged fp32) =================
__global__ void edge1_kernel(float* ws, const int* idx) {
    __shared__ __align__(16) float g1T[KK*64];
    __shared__ __align__(16) float h1L[64*21];
    __shared__ __align__(16) float hrT[KK*64];
    __shared__ __align__(16) float attL[64*21];
    __shared__ float xcL[19];
    __shared__ int idxL[KK];
    int tid = threadIdx.x;
    int b = blockIdx.x >> 11, n = blockIdx.x & 2047;
    const float* xb = ws + O_XMAN + b*19*NN;
    if (tid < KK) idxL[tid] = idx[(b*NN + n)*KK + tid] & (NN-1);
    if (tid < 19) xcL[tid] = xb[tid*NN + n];
    __syncthreads();
    for (int i = tid; i < KK*64; i += 64) {
        int k = i >> 6, c = i & 63;
        int j = idxL[k];
        float v = 0.f;
        if (c < 19) v = xb[c*NN + j];
        else if (c < 38) v = xcL[c-19];
        else if (c < 57) v = xcL[c-38] - xb[(c-38)*NN + j];
        g1T[i] = v;
    }
    __syncthreads();
    int ro = tid & 15, kb = (tid >> 4) * 5;
    const float* w1p = ws + O_W1P;
    float acc[4][5];
    #pragma unroll
    for (int j = 0; j < 4; ++j)
        #pragma unroll
        for (int kk = 0; kk < 5; ++kk) acc[j][kk] = 0.f;
    for (int c4 = 0; c4 < 16; ++c4) {
        float4 gv[5], wv[4];
        #pragma unroll
        for (int kk = 0; kk < 5; ++kk) gv[kk] = *(const float4*)&g1T[(kb+kk)*64 + c4*4];
        #pragma unroll
        for (int j = 0; j < 4; ++j) wv[j] = *(const float4*)&w1p[(ro + 16*j)*64 + c4*4];
        #pragma unroll
        for (int j = 0; j < 4; ++j)
            #pragma unroll
            for (int kk = 0; kk < 5; ++kk)
                acc[j][kk] += wv[j].x*gv[kk].x + wv[j].y*gv[kk].y + wv[j].z*gv[kk].z + wv[j].w*gv[kk].w;
    }
    #pragma unroll
    for (int j = 0; j < 4; ++j) {
        int r = ro + 16*j;
        float s1 = ws[O_BN1SC + r], h1s = ws[O_BN1SH + r];
        float ps = ws[O_P1SC + r], ph = ws[O_P1SH + r];
        #pragma unroll
        for (int kk = 0; kk < 5; ++kk) {
            float v = acc[j][kk]*s1 + h1s;
            v = v > 0.f ? v : 0.2f*v;
            h1L[r*21 + kb + kk] = v;
            float hv = v*ps + ph;
            hrT[(kb+kk)*64 + r] = hv > 0.f ? hv : 0.f;
        }
    }
    __syncthreads();
    const float* p1w = ws + O_P1W;
    float ac2[4][5];
    #pragma unroll
    for (int j = 0; j < 4; ++j)
        #pragma unroll
        for (int kk = 0; kk < 5; ++kk) ac2[j][kk] = 0.f;
    for (int c4 = 0; c4 < 16; ++c4) {
        float4 gv[5], wv[4];
        #pragma unroll
        for (int kk = 0; kk < 5; ++kk) gv[kk] = *(const float4*)&hrT[(kb+kk)*64 + c4*4];
        #pragma unroll
        for (int j = 0; j < 4; ++j) wv[j] = *(const float4*)&p1w[(ro + 16*j)*64 + c4*4];
        #pragma unroll
        for (int j = 0; j < 4; ++j)
            #pragma unroll
            for (int kk = 0; kk < 5; ++kk)
                ac2[j][kk] += wv[j].x*gv[kk].x + wv[j].y*gv[kk].y + wv[j].z*gv[kk].z + wv[j].w*gv[kk].w;
    }
    #pragma unroll
    for (int j = 0; j < 4; ++j) {
        int r = ro + 16*j;
        float pb = ws[O_P1B + r];
        #pragma unroll
        for (int kk = 0; kk < 5; ++kk) attL[r*21 + kb + kk] = ac2[j][kk] + pb;
    }
    __syncthreads();
    {
        int o = tid;
        float av[KK]; float mx = -3.0e38f;
        #pragma unroll
        for (int k = 0; k < KK; ++k) { av[k] = attL[o*21 + k]; mx = fmaxf(mx, av[k]); }
        float ssum = 0.f;
        #pragma unroll
        for (int k = 0; k < KK; ++k) { av[k] = expf(av[k] - mx); ssum += av[k]; }
        float outv = 0.f;
        #pragma unroll
        for (int k = 0; k < KK; ++k) outv += h1L[o*21 + k] * (av[k]/ssum);
        float* xc1 = ws + O_XC1 + b*83*NN;
        xc1[(19+o)*NN + n] = outv;
        if (tid < 19) xc1[tid*NN + n] = xcL[tid];
    }
}

// ================= xpose1: xc1 [b][83][2048] -> xc1T [b][2048][84] (pad col 83 = 0) ===========
__global__ __launch_bounds__(256) void xpose1_kernel(float* ws) {
    __shared__ float t[84*129];
    int tid = threadIdx.x;
    int b = blockIdx.x >> 4;
    int n0 = (blockIdx.x & 15) << 7;
    const float* xc1 = ws + O_XC1 + (size_t)b*83*NN;
    for (int i = tid; i < 84*128; i += 256) {
        int c = i >> 7, nn = i & 127;
        t[c*129 + nn] = (c < 83) ? xc1[c*NN + n0 + nn] : 0.f;
    }
    __syncthreads();
    float* xT = ws + O_XC2 + (size_t)b*512*NN;   // xc1T lives in XC2 rows 0..83-ish (pre-mlp)
    for (int i = tid; i < 128*84; i += 256) {
        int nn = i / 84, c = i - nn*84;
        xT[(size_t)(n0+nn)*84 + c] = t[c*129 + nn];
    }
}

// ================= edge2 MFMA: 4 points/block, bf16 matmuls, fp32 acc ==================
// GEMM1: h2(256x80) = W2b(256x288) @ g2b(288x80);  GEMM2: att = P2Wb(256x256) @ hrb(256x80)
// A-frag (lane): A[m=l&15][k=quad*8+j];  B-frag: B[k=quad*8+j][n=l&15];
// C/D: row=quad*4+reg, col=l&15  [per guide §3, measured m89/m91]
__global__ __launch_bounds__(256, 1) void edge2_mfma_kernel(float* ws, const int* idx) {
    __shared__ __align__(16) float sbuf[21504];   // union: g2b ush[80][296] / hrb ush[80][264] / attL f32[256][84]
    __shared__ float scal[5*256];
    __shared__ int idxL[80];
    ushort16_t* g2b = (ushort16_t*)sbuf;          // stride 296 (2-way bank alias only)
    ushort16_t* hrb = (ushort16_t*)sbuf;          // stride 264
    float* attL = sbuf;                           // stride 84

    int tid = threadIdx.x;
    int b  = blockIdx.x >> 9;
    int ng = blockIdx.x & 511;
    int n0 = ng << 2;

    scal[tid]        = ws[O_BN2SC + tid];
    scal[256 + tid]  = ws[O_BN2SH + tid];
    scal[512 + tid]  = ws[O_P2SC + tid];
    scal[768 + tid]  = ws[O_P2SH + tid];
    scal[1024 + tid] = ws[O_P2B + tid];
    if (tid < 80) idxL[tid] = idx[(b*NN + n0 + tid/20)*KK + (tid%20)] & (NN-1);
    {   // zero g2b (pads must be 0: 0*NaN poisons acc)
        uint32* gz = (uint32*)sbuf;
        for (int i = tid; i < 11840; i += 256) gz[i] = 0;
    }
    __syncthreads();

    // gather from xc1T (contiguous 16B chunks per (col, c4))
    const float* xT = ws + O_XC2 + (size_t)b*512*NN;
    for (int i = tid; i < 80*21; i += 256) {
        int col = i / 21, c4 = (i - col*21) * 4;
        int p = col / 20;
        int j = idxL[col];
        float4 nb = *(const float4*)&xT[(size_t)j*84 + c4];
        float4 ce = *(const float4*)&xT[(size_t)(n0+p)*84 + c4];
        ushort16_t* g = g2b + col*296;
        st4bf(g + c4,        nb.x, nb.y, nb.z, nb.w);
        st4bf(g + 88 + c4,   ce.x, ce.y, ce.z, ce.w);
        st4bf(g + 176 + c4,  ce.x-nb.x, ce.y-nb.y, ce.z-nb.z, ce.w-nb.w);
    }
    __syncthreads();

    int lane = tid & 63, wv = tid >> 6;
    int quad = lane >> 4, l15 = lane & 15;
    const ushort16_t* w2b  = (const ushort16_t*)(ws + O_W2B16);
    const ushort16_t* p2wb = (const ushort16_t*)(ws + O_P2W16);

    floatx4 acc[4][5];
    #pragma unroll
    for (int mt = 0; mt < 4; ++mt)
        #pragma unroll
        for (int nt = 0; nt < 5; ++nt) acc[mt][nt] = (floatx4){0.f,0.f,0.f,0.f};

    // GEMM1: K=288 (9 steps)
    for (int kt = 0; kt < 9; ++kt) {
        int c0 = kt*32 + quad*8;
        short8 a[4], bb[5];
        #pragma unroll
        for (int mt = 0; mt < 4; ++mt)
            a[mt] = *(const short8*)&w2b[(wv*64 + mt*16 + l15)*288 + c0];
        #pragma unroll
        for (int nt = 0; nt < 5; ++nt)
            bb[nt] = *(const short8*)&g2b[(nt*16 + l15)*296 + c0];
        #pragma unroll
        for (int mt = 0; mt < 4; ++mt)
            #pragma unroll
            for (int nt = 0; nt < 5; ++nt)
                acc[mt][nt] = __builtin_amdgcn_mfma_f32_16x16x32_bf16(a[mt], bb[nt], acc[mt][nt], 0, 0, 0);
    }
    __syncthreads();   // all g2b reads done (buffer reused as hrb)

    // h2 = lrelu(acc*sc+sh); hr = relu(h2*ps+ph) -> hrb bf16 [col][k=row]
    float h2s[4][5][4];
    #pragma unroll
    for (int mt = 0; mt < 4; ++mt) {
        int k0 = wv*64 + mt*16 + quad*4;
        #pragma unroll
        for (int nt = 0; nt < 5; ++nt) {
            int col = nt*16 + l15;
            float hv[4];
            #pragma unroll
            for (int r = 0; r < 4; ++r) {
                int row = k0 + r;
                float v = acc[mt][nt][r]*scal[row] + scal[256+row];
                v = v > 0.f ? v : 0.2f*v;
                h2s[mt][nt][r] = v;
                float h = v*scal[512+row] + scal[768+row];
                hv[r] = fmaxf(h, 0.f);
            }
            st4bf(hrb + col*264 + k0, hv[0], hv[1], hv[2], hv[3]);
        }
    }
    __syncthreads();

    // GEMM2: K=256 (8 steps)
    floatx4 acc2[4][5];
    #pragma unroll
    for (int mt = 0; mt < 4; ++mt)
        #pragma unroll
        for (int nt = 0; nt < 5; ++nt) acc2[mt][nt] = (floatx4){0.f,0.f,0.f,0.f};
    for (int kt = 0; kt < 8; ++kt) {
        int c0 = kt*32 + quad*8;
        short8 a[4], bb[5];
        #pragma unroll
        for (int mt = 0; mt < 4; ++mt)
            a[mt] = *(const short8*)&p2wb[(wv*64 + mt*16 + l15)*256 + c0];
        #pragma unroll
        for (int nt = 0; nt < 5; ++nt)
            bb[nt] = *(const short8*)&hrb[(nt*16 + l15)*264 + c0];
        #pragma unroll
        for (int mt = 0; mt < 4; ++mt)
            #pragma unroll
            for (int nt = 0; nt < 5; ++nt)
                acc2[mt][nt] = __builtin_amdgcn_mfma_f32_16x16x32_bf16(a[mt], bb[nt], acc2[mt][nt], 0, 0, 0);
    }
    __syncthreads();   // hrb reads done (buffer reused as attL)

    // att -> attL
    #pragma unroll
    for (int mt = 0; mt < 4; ++mt) {
        int k0 = wv*64 + mt*16 + quad*4;
        #pragma unroll
        for (int nt = 0; nt < 5; ++nt) {
            int col = nt*16 + l15;
            #pragma unroll
            for (int r = 0; r < 4; ++r) {
                int row = k0 + r;
                attL[row*84 + col] = acc2[mt][nt][r] + scal[1024+row];
            }
        }
    }
    __syncthreads();

    // softmax over k per (row, p) -> coef in place
    #pragma unroll
    for (int q = 0; q < 4; ++q) {
        int pr = tid + 256*q;           // 0..1023
        int row = pr >> 2, p = pr & 3;
        float av[KK]; float mx = -3.0e38f;
        #pragma unroll
        for (int k = 0; k < KK; ++k) { av[k] = attL[row*84 + p*20 + k]; mx = fmaxf(mx, av[k]); }
        float ssum = 0.f;
        #pragma unroll
        for (int k = 0; k < KK; ++k) { av[k] = expf(av[k] - mx); ssum += av[k]; }
        float inv = 1.f / ssum;
        #pragma unroll
        for (int k = 0; k < KK; ++k) attL[row*84 + p*20 + k] = av[k] * inv;
    }
    __syncthreads();

    // products in place: attL <- h2 * coef
    #pragma unroll
    for (int mt = 0; mt < 4; ++mt) {
        int k0 = wv*64 + mt*16 + quad*4;
        #pragma unroll
        for (int nt = 0; nt < 5; ++nt) {
            int col = nt*16 + l15;
            #pragma unroll
            for (int r = 0; r < 4; ++r)
                attL[(k0+r)*84 + col] *= h2s[mt][nt][r];
        }
    }
    __syncthreads();

    // reduce over k, write xp2 -> XC2 rows 256..511
    float* xout = ws + O_XC2 + (size_t)b*512*NN;
    #pragma unroll
    for (int q = 0; q < 4; ++q) {
        int pr = tid + 256*q;
        int row = pr >> 2, p = pr & 3;
        float sacc = 0.f;
        #pragma unroll
        for (int k = 0; k < KK; ++k) sacc += attL[row*84 + p*20 + k];
        xout[(size_t)(256+row)*NN + n0 + p] = sacc;
    }
}

// ================= final: out = lrelu(bn3(w3 @ x_c2)) -> fp32 =================
__global__ void final_kernel(const float* ws, float* out) {
    __shared__ __align__(16) float tileF[512*16];
    int tid = threadIdx.x;
    int b = blockIdx.x >> 7;
    int n0 = (blockIdx.x & 127) << 4;
    const float* xc2 = ws + O_XC2 + b*512*NN;
    for (int i = tid; i < 512*16; i += 256) {
        int c = i >> 4, nn = i & 15;
        tileF[i] = xc2[c*NN + n0 + nn];
    }
    __syncthreads();
    const float* w3p = ws + O_W3P;
    int r0 = tid*2, r1 = r0 + 1;
    float acc0[16], acc1[16];
    #pragma unroll
    for (int q = 0; q < 16; ++q) { acc0[q] = 0.f; acc1[q] = 0.f; }
    #pragma unroll 4
    for (int c = 0; c < 512; ++c) {
        float w0 = w3p[r0*512 + c], w1v = w3p[r1*512 + c];
        const float4* tr = (const float4*)&tileF[c*16];
        #pragma unroll
        for (int q = 0; q < 4; ++q) {
            float4 t = tr[q];
            acc0[q*4+0] += w0*t.x;  acc0[q*4+1] += w0*t.y;  acc0[q*4+2] += w0*t.z;  acc0[q*4+3] += w0*t.w;
            acc1[q*4+0] += w1v*t.x; acc1[q*4+1] += w1v*t.y; acc1[q*4+2] += w1v*t.z; acc1[q*4+3] += w1v*t.w;
        }
    }
    float s0 = ws[O_BN3SC + r0], q0 = ws[O_BN3SH + r0];
    float s1 = ws[O_BN3SC + r1], q1 = ws[O_BN3SH + r1];
    float* ob = out + b*512*NN;
    #pragma unroll
    for (int nn = 0; nn < 16; ++nn) {
        float v = acc0[nn]*s0 + q0; v = v > 0.f ? v : 0.2f*v;
        ob[r0*NN + n0 + nn] = v;
        float u = acc1[nn]*s1 + q1; u = u > 0.f ? u : 0.2f*u;
        ob[r1*NN + n0 + nn] = u;
    }
}

extern "C" void kernel_launch(void* const* d_in, const int* in_sizes, int n_in,
                              void* d_out, int out_size, void* d_ws, size_t ws_size,
                              hipStream_t stream) {
    float* ws = (float*)d_ws;
    float* out = (float*)d_out;
    float* pkv = ws + O_PKV;
    int*   pki = (int*)(ws + O_PKI);

    detect_kernel<<<1, 64, 0, stream>>>(d_in[0], (int*)ws + O_FLAG);
    prep_kernel<<<64, 256, 0, stream>>>(d_in[1], d_in[2], d_in[3], d_in[4], d_in[5], d_in[6],
                                        d_in[7], d_in[8], d_in[9], d_in[10], d_in[11], d_in[12],
                                        d_in[13], d_in[14], d_in[15], d_in[16], d_in[17], d_in[18],
                                        d_in[19], d_in[20], d_in[21], ws);
    lafe_kernel<<<64, 256, 0, stream>>>(d_in[0], ws);
    knn_part_kernel<19, 256, 2><<<128, 256, 0, stream>>>(ws + O_XMAN, pkv, pki);
    knn_merge_kernel<2><<<64, 256, 0, stream>>>(pkv, pki, (int*)(ws + O_IDX2));
    edge1_kernel<<<BB*NN, 64, 0, stream>>>(ws, (const int*)(ws + O_IDX2));
    knn_part_kernel<83, 128, 4><<<256, 256, 0, stream>>>(ws + O_XC1, pkv, pki);
    knn_merge_kernel<4><<<64, 256, 0, stream>>>(pkv, pki, (int*)(ws + O_IDX3));
    // transpose xc1 into XC2 scratch (after knn scratch consumed), then MFMA edge2
    xpose1_kernel<<<128, 256, 0, stream>>>(ws);
    edge2_mfma_kernel<<<BB*512, 256, 0, stream>>>(ws, (const int*)(ws + O_IDX3));
    // mlp overwrites xc1T region (XC2 rows 0..255) only after edge2 is done
    mlp_kernel<<<BB*NN, 256, 0, stream>>>(ws);
    final_kernel<<<BB*(NN/16), 256, 0, stream>>>(ws, out);
}

// Round 7
// 2245.774 us; speedup vs baseline: 16.7655x; 1.3538x over previous
//
#include <hip/hip_runtime.h>
#include <hip/hip_bf16.h>
#include <math.h>

typedef __hip_bfloat16 bf16;
typedef unsigned short ushort16_t;
typedef unsigned int uint32;
typedef __attribute__((ext_vector_type(8))) short short8;
typedef __attribute__((ext_vector_type(4))) float floatx4;

#define BB 8
#define NN 2048
#define KK 20

// ---- workspace layout (float offsets) ----
#define O_XMAN  0                        // [8][19][2048]  rows 0..2 = x (fp32), rows 3..18 = lafe out
#define O_XC1   311296                   // [8][83][2048]
#define O_XC2   1671168                  // [8][512][2048] rows 0..255=x_mlp, 256..511=xp2
                                         // reused: knn partial scratch, then xc1T[b][2048][84]
#define O_IDX2  10059776                 // int [8][2048][20]
#define O_IDX3  10387456                 // int [8][2048][20] (also temp home for lafe knn idx)
#define O_MLPW  10715136                 // [256][20] padded
#define O_MLPSC 10720256
#define O_MLPSH 10720512
#define O_W1P   10720768                 // [64][64] padded
#define O_BN1SC 10724864
#define O_BN1SH 10724928
#define O_P1SC  10724992
#define O_P1SH  10725056
#define O_P1W   10725120                 // [64][64]
#define O_P1B   10729216
#define O_W2P   10729280                 // [256][256] padded fp32 (unused by MFMA path)
#define O_BN2SC 10794816
#define O_BN2SH 10795072
#define O_P2SC  10795328
#define O_P2SH  10795584
#define O_P2W   10795840                 // [256][256] fp32
#define O_P2B   10861376
#define O_W3P   10861632                 // [512][512]
#define O_BN3SC 11123776
#define O_BN3SH 11124288
#define O_LA    11124800                 // w1[48] b1[16] w2[48] b2[16] w3[16] b3[1]
#define O_FLAG  11124960                 // int: 1 if inputs are fp32, 0 if bf16
#define O_W2B16 11125760                 // ushort [256][288] bf16 w2, segment-padded
#define O_P2W16 11162624                 // ushort [256][256] bf16 p2w

// knn partial scratch inside XC2 region (consumed before xpose/mlp/edge2 write XC2)
// sized for S=8: [8][8][2048][20] = 2,621,440 each; 5.24M total < 8.4M XC2 region
#define O_PKV   O_XC2
#define O_PKI   (O_XC2 + 2621440)

__device__ __forceinline__ float ldin(const void* p, int i, int f32) {
    return f32 ? ((const float*)p)[i]
               : __bfloat162float(((const bf16*)p)[i]);
}

__device__ __forceinline__ ushort16_t f2bf(float v) {
    union { bf16 h; ushort16_t u; } x; x.h = __float2bfloat16(v); return x.u;
}

__device__ __forceinline__ void st4bf(ushort16_t* p, float a, float b, float c, float d) {
    uint2 v;
    v.x = (uint32)f2bf(a) | ((uint32)f2bf(b) << 16);
    v.y = (uint32)f2bf(c) | ((uint32)f2bf(d) << 16);
    *(uint2*)p = v;
}

// top-k insertion, compile-time indices only (VGPR-resident with __launch_bounds__)
__device__ __forceinline__ void topk_ins(float (&tv)[KK], int (&ti)[KK], float d, int m) {
    if (d > tv[KK-1]) {
        tv[KK-1] = d; ti[KK-1] = m;
        #pragma unroll
        for (int j = KK-1; j > 0; --j) {
            if (tv[j] > tv[j-1]) {
                float tf = tv[j-1]; tv[j-1] = tv[j]; tv[j] = tf;
                int   tx = ti[j-1]; ti[j-1] = ti[j]; ti[j] = tx;
            }
        }
    }
}

// ============ detect: are inputs fp32 or bf16? ============
__global__ void detect_kernel(const void* x, int* flag) {
    if (threadIdx.x == 0 && blockIdx.x == 0) {
        const unsigned short* u = (const unsigned short*)x;
        int bad = 0;
        for (int i = 0; i < 64; ++i) {
            int e = (u[i] >> 7) & 0xFF;
            if (e >= 0x86) bad++;
        }
        *flag = (bad > 0) ? 1 : 0;
    }
}

// ================= prep =================
__global__ void prep_kernel(
    const void* la_w1, const void* la_b1, const void* la_w2, const void* la_b2,
    const void* la_w3, const void* la_b3,
    const void* mlp_w, const void* mlp_b, const void* mlp_bn,
    const void* w1, const void* bn1, const void* w2, const void* bn2,
    const void* w3, const void* bn3,
    const void* p1_bn, const void* p1_w, const void* p1_b,
    const void* p2_bn, const void* p2_w, const void* p2_b,
    float* ws)
{
    const int f32 = ((const int*)ws)[O_FLAG];
    int gid = blockIdx.x * blockDim.x + threadIdx.x;
    int gsz = gridDim.x * blockDim.x;

    for (int i = gid; i < 256*20; i += gsz) {
        int o = i / 20, c = i - o*20;
        ws[O_MLPW + i] = (c < 19) ? ldin(mlp_w, o*19 + c, f32) : 0.f;
    }
    for (int c = gid; c < 256; c += gsz) {
        float g = ldin(mlp_bn, c, f32), be = ldin(mlp_bn, 256+c, f32);
        float m = ldin(mlp_bn, 512+c, f32), vv = ldin(mlp_bn, 768+c, f32);
        float s = g / sqrtf(vv + 1e-5f);
        ws[O_MLPSC + c] = s;
        ws[O_MLPSH + c] = be + (ldin(mlp_b, c, f32) - m) * s;
    }
    for (int i = gid; i < 64*64; i += gsz) {
        int o = i >> 6, c = i & 63;
        ws[O_W1P + i] = (c < 57) ? ldin(w1, o*57 + c, f32) : 0.f;
    }
    for (int c = gid; c < 64; c += gsz) {
        float g = ldin(bn1, c, f32), be = ldin(bn1, 64+c, f32);
        float m = ldin(bn1, 128+c, f32), vv = ldin(bn1, 192+c, f32);
        float s = g / sqrtf(vv + 1e-5f);
        ws[O_BN1SC + c] = s; ws[O_BN1SH + c] = be - m*s;
        float g2 = ldin(p1_bn, c, f32), be2 = ldin(p1_bn, 64+c, f32);
        float m2 = ldin(p1_bn, 128+c, f32), vv2 = ldin(p1_bn, 192+c, f32);
        float s2 = g2 / sqrtf(vv2 + 1e-5f);
        ws[O_P1SC + c] = s2; ws[O_P1SH + c] = be2 - m2*s2;
        ws[O_P1B + c] = ldin(p1_b, c, f32);
    }
    for (int i = gid; i < 64*64; i += gsz) ws[O_P1W + i] = ldin(p1_w, i, f32);
    for (int c = gid; c < 256; c += gsz) {
        float g = ldin(bn2, c, f32), be = ldin(bn2, 256+c, f32);
        float m = ldin(bn2, 512+c, f32), vv = ldin(bn2, 768+c, f32);
        float s = g / sqrtf(vv + 1e-5f);
        ws[O_BN2SC + c] = s; ws[O_BN2SH + c] = be - m*s;
        float g2 = ldin(p2_bn, c, f32), be2 = ldin(p2_bn, 256+c, f32);
        float m2 = ldin(p2_bn, 512+c, f32), vv2 = ldin(p2_bn, 768+c, f32);
        float s2 = g2 / sqrtf(vv2 + 1e-5f);
        ws[O_P2SC + c] = s2; ws[O_P2SH + c] = be2 - m2*s2;
        ws[O_P2B + c] = ldin(p2_b, c, f32);
    }
    for (int i = gid; i < 512*512; i += gsz) ws[O_W3P + i] = ldin(w3, i, f32);
    for (int c = gid; c < 512; c += gsz) {
        float g = ldin(bn3, c, f32), be = ldin(bn3, 512+c, f32);
        float m = ldin(bn3, 1024+c, f32), vv = ldin(bn3, 1536+c, f32);
        float s = g / sqrtf(vv + 1e-5f);
        ws[O_BN3SC + c] = s; ws[O_BN3SH + c] = be - m*s;
    }
    for (int i = gid; i < 48; i += gsz) ws[O_LA + i]       = ldin(la_w1, i, f32);
    for (int i = gid; i < 16; i += gsz) ws[O_LA + 48 + i]  = ldin(la_b1, i, f32);
    for (int i = gid; i < 48; i += gsz) ws[O_LA + 64 + i]  = ldin(la_w2, i, f32);
    for (int i = gid; i < 16; i += gsz) ws[O_LA + 112 + i] = ldin(la_b2, i, f32);
    for (int i = gid; i < 16; i += gsz) ws[O_LA + 128 + i] = ldin(la_w3, i, f32);
    if (gid == 0) ws[O_LA + 144] = ldin(la_b3, 0, f32);

    // bf16 weights for edge2 MFMA (w2b: [256][288] segment-padded 83->88)
    ushort16_t* w2b = (ushort16_t*)(ws + O_W2B16);
    for (int i = gid; i < 256*288; i += gsz) {
        int row = i / 288, cp = i - row*288;
        int s = cp / 88, cc = cp - s*88;
        float v = (s < 3 && cc < 83) ? ldin(w2, row*249 + s*83 + cc, f32) : 0.f;
        w2b[i] = f2bf(v);
    }
    ushort16_t* pwb = (ushort16_t*)(ws + O_P2W16);
    for (int i = gid; i < 256*256; i += gsz) pwb[i] = f2bf(ldin(p2_w, i, f32));
}

// ================= xconv: x -> fp32 into XMAN rows 0..2 =================
__global__ __launch_bounds__(256) void xconv_kernel(const void* x, float* ws) {
    const int f32 = ((const int*)ws)[O_FLAG];
    int gid = blockIdx.x*256 + threadIdx.x;     // 0 .. 8*3*2048-1
    int b = gid / (3*NN), r = gid - b*3*NN;
    ws[O_XMAN + b*19*NN + r] = ldin(x, gid, f32);
}

// ====== knn partial: C channels, row-stride CS, split S over candidates ======
template<int C, int CS, int TILE, int S>
__global__ __launch_bounds__(256, 1) void knn_part_kernel(const float* feat, float* pv, int* pi) {
    __shared__ __align__(16) float tile[C * TILE + TILE];
    float* xxt = tile + C * TILE;
    int tid = threadIdx.x;
    int s = blockIdx.x & (S-1);
    int bc = blockIdx.x / S;
    int b = bc >> 3;
    int n = ((bc & 7) << 8) + tid;
    const float* fb = feat + b * CS * NN;
    float myf[C];
    #pragma unroll
    for (int c = 0; c < C; ++c) myf[c] = fb[c*NN + n];
    float xxn = 0.f;
    #pragma unroll
    for (int c = 0; c < C; ++c) xxn += myf[c]*myf[c];
    float tv[KK]; int ti[KK];
    #pragma unroll
    for (int k = 0; k < KK; ++k) { tv[k] = -3.0e38f; ti[k] = 0; }
    const int T0 = s * (NN / S / TILE), T1 = (s+1) * (NN / S / TILE);
    for (int t = T0; t < T1; ++t) {
        __syncthreads();
        for (int i = tid; i < C*TILE; i += 256) {
            int c = i / TILE, j = i - c*TILE;
            tile[i] = fb[c*NN + t*TILE + j];
        }
        __syncthreads();
        for (int j = tid; j < TILE; j += 256) {
            float sq = 0.f;
            #pragma unroll
            for (int c = 0; c < C; ++c) sq += tile[c*TILE + j]*tile[c*TILE + j];
            xxt[j] = sq;
        }
        __syncthreads();
        for (int j4 = 0; j4 < TILE/4; ++j4) {
            float4 dot = make_float4(0.f, 0.f, 0.f, 0.f);
            #pragma unroll
            for (int c = 0; c < C; ++c) {
                float4 tvv = *(const float4*)&tile[c*TILE + j4*4];
                float f = myf[c];
                dot.x += f*tvv.x; dot.y += f*tvv.y; dot.z += f*tvv.z; dot.w += f*tvv.w;
            }
            float4 xxv = *(const float4*)&xxt[j4*4];
            int mb = t*TILE + j4*4;
            topk_ins(tv, ti, 2.f*dot.x - xxn - xxv.x, mb+0);
            topk_ins(tv, ti, 2.f*dot.y - xxn - xxv.y, mb+1);
            topk_ins(tv, ti, 2.f*dot.z - xxn - xxv.z, mb+2);
            topk_ins(tv, ti, 2.f*dot.w - xxn - xxv.w, mb+3);
        }
    }
    long base = ((long)(s*BB + b)*NN + n)*KK;
    #pragma unroll
    for (int k = 0; k < KK; ++k) { pv[base + k] = tv[k]; pi[base + k] = ti[k]; }
}

template<int S>
__global__ __launch_bounds__(256, 1) void knn_merge_kernel(const float* pv, const int* pi, int* idxout) {
    int gid = blockIdx.x*256 + threadIdx.x;
    float tv[KK]; int ti[KK];
    #pragma unroll
    for (int k = 0; k < KK; ++k) { tv[k] = -3.0e38f; ti[k] = 0; }
    #pragma unroll
    for (int s = 0; s < S; ++s) {
        long base = ((long)s*BB*NN + gid)*KK;
        #pragma unroll
        for (int k = 0; k < KK; ++k)
            topk_ins(tv, ti, pv[base + k], pi[base + k]);
    }
    #pragma unroll
    for (int k = 0; k < KK; ++k) idxout[(long)gid*KK + k] = ti[k];
}

// ================= lafe attention (post-knn): XMAN rows 0..2 + idx -> rows 3..18 ==========
__global__ __launch_bounds__(256, 1) void lafe_att_kernel(float* ws, const int* idx) {
    __shared__ float xs0[NN], xs1[NN], xs2[NN];
    int tid = threadIdx.x;
    int b = blockIdx.x >> 3;
    int n = ((blockIdx.x & 7) << 8) + tid;
    float* xm = ws + O_XMAN + b*19*NN;
    for (int i = tid; i < NN; i += 256) {
        xs0[i] = xm[i]; xs1[i] = xm[NN + i]; xs2[i] = xm[2*NN + i];
    }
    __syncthreads();
    float a0 = xs0[n], a1 = xs1[n], a2 = xs2[n];
    int ti[KK];
    #pragma unroll
    for (int k = 0; k < KK; ++k) ti[k] = idx[(b*NN + n)*KK + k] & (NN-1);
    const float* wl = ws + O_LA;
    float sa = wl[144];
    #pragma unroll
    for (int o = 0; o < 16; ++o) {
        float nf = wl[o*3+0]*a0 + wl[o*3+1]*a1 + wl[o*3+2]*a2 + wl[48+o];
        sa += wl[128+o]*nf;
    }
    float lg[KK]; float mx = -3.0e38f;
    #pragma unroll
    for (int k = 0; k < KK; ++k) {
        int m = ti[k];
        float d0 = a0 - xs0[m], d1 = a1 - xs1[m], d2 = a2 - xs2[m];
        float na = wl[144];
        #pragma unroll
        for (int o = 0; o < 16; ++o) {
            float ef = wl[64+o*3+0]*d0 + wl[64+o*3+1]*d1 + wl[64+o*3+2]*d2 + wl[112+o];
            na += wl[128+o]*ef;
        }
        float t = sa + na;
        t = t > 0.f ? t : 0.01f*t;
        lg[k] = t; mx = fmaxf(mx, t);
    }
    float ssum = 0.f;
    #pragma unroll
    for (int k = 0; k < KK; ++k) { lg[k] = expf(lg[k] - mx); ssum += lg[k]; }
    float vals[16];
    #pragma unroll
    for (int o = 0; o < 16; ++o) vals[o] = 0.f;
    #pragma unroll
    for (int k = 0; k < KK; ++k) {
        float coef = lg[k] / ssum;
        int m = ti[k];
        float d0 = a0 - xs0[m], d1 = a1 - xs1[m], d2 = a2 - xs2[m];
        #pragma unroll
        for (int o = 0; o < 16; ++o) {
            float ef = wl[64+o*3+0]*d0 + wl[64+o*3+1]*d1 + wl[64+o*3+2]*d2 + wl[112+o];
            vals[o] += coef * ef;
        }
    }
    #pragma unroll
    for (int o = 0; o < 16; ++o) {
        float v = vals[o];
        xm[(3+o)*NN + n] = v > 0.f ? v : expm1f(v);
    }
}

// ================= mlp =================
__global__ void mlp_kernel(float* ws) {
    __shared__ __align__(16) float xv[20];
    int tid = threadIdx.x;
    int b = blockIdx.x >> 11, n = blockIdx.x & 2047;
    if (tid < 20) xv[tid] = (tid < 19) ? ws[O_XMAN + b*19*NN + tid*NN + n] : 0.f;
    __syncthreads();
    const float* mw = ws + O_MLPW;
    float acc = 0.f;
    #pragma unroll
    for (int c4 = 0; c4 < 5; ++c4) {
        float4 w = *(const float4*)&mw[tid*20 + c4*4];
        float4 g = *(const float4*)&xv[c4*4];
        acc += w.x*g.x + w.y*g.y + w.z*g.z + w.w*g.w;
    }
    float v = acc * ws[O_MLPSC + tid] + ws[O_MLPSH + tid];
    ws[O_XC2 + b*512*NN + tid*NN + n] = fmaxf(v, 0.f);
}

// ================= edge1 (fp32) =================
__global__ void edge1_kernel(float* ws, const int* idx) {
    __shared__ __align__(16) float g1T[KK*64];
    __shared__ __align__(16) float h1L[64*21];
    __shared__ __align__(16) float hrT[KK*64];
    __shared__ __align__(16) float attL[64*21];
    __shared__ float xcL[19];
    __shared__ int idxL[KK];
    int tid = threadIdx.x;
    int b = blockIdx.x >> 11, n = blockIdx.x & 2047;
    const float* xb = ws + O_XMAN + b*19*NN;
    if (tid < KK) idxL[tid] = idx[(b*NN + n)*KK + tid] & (NN-1);
    if (tid < 19) xcL[tid] = xb[tid*NN + n];
    __syncthreads();
    for (int i = tid; i < KK*64; i += 64) {
        int k = i >> 6, c = i & 63;
        int j = idxL[k];
        float v = 0.f;
        if (c < 19) v = xb[c*NN + j];
        else if (c < 38) v = xcL[c-19];
        else if (c < 57) v = xcL[c-38] - xb[(c-38)*NN + j];
        g1T[i] = v;
    }
    __syncthreads();
    int ro = tid & 15, kb = (tid >> 4) * 5;
    const float* w1p = ws + O_W1P;
    float acc[4][5];
    #pragma unroll
    for (int j = 0; j < 4; ++j)
        #pragma unroll
        for (int kk = 0; kk < 5; ++kk) acc[j][kk] = 0.f;
    for (int c4 = 0; c4 < 16; ++c4) {
        float4 gv[5], wv[4];
        #pragma unroll
        for (int kk = 0; kk < 5; ++kk) gv[kk] = *(const float4*)&g1T[(kb+kk)*64 + c4*4];
        #pragma unroll
        for (int j = 0; j < 4; ++j) wv[j] = *(const float4*)&w1p[(ro + 16*j)*64 + c4*4];
        #pragma unroll
        for (int j = 0; j < 4; ++j)
            #pragma unroll
            for (int kk = 0; kk < 5; ++kk)
                acc[j][kk] += wv[j].x*gv[kk].x + wv[j].y*gv[kk].y + wv[j].z*gv[kk].z + wv[j].w*gv[kk].w;
    }
    #pragma unroll
    for (int j = 0; j < 4; ++j) {
        int r = ro + 16*j;
        float s1 = ws[O_BN1SC + r], h1s = ws[O_BN1SH + r];
        float ps = ws[O_P1SC + r], ph = ws[O_P1SH + r];
        #pragma unroll
        for (int kk = 0; kk < 5; ++kk) {
            float v = acc[j][kk]*s1 + h1s;
            v = v > 0.f ? v : 0.2f*v;
            h1L[r*21 + kb + kk] = v;
            float hv = v*ps + ph;
            hrT[(kb+kk)*64 + r] = hv > 0.f ? hv : 0.f;
        }
    }
    __syncthreads();
    const float* p1w = ws + O_P1W;
    float ac2[4][5];
    #pragma unroll
    for (int j = 0; j < 4; ++j)
        #pragma unroll
        for (int kk = 0; kk < 5; ++kk) ac2[j][kk] = 0.f;
    for (int c4 = 0; c4 < 16; ++c4) {
        float4 gv[5], wv[4];
        #pragma unroll
        for (int kk = 0; kk < 5; ++kk) gv[kk] = *(const float4*)&hrT[(kb+kk)*64 + c4*4];
        #pragma unroll
        for (int j = 0; j < 4; ++j) wv[j] = *(const float4*)&p1w[(ro + 16*j)*64 + c4*4];
        #pragma unroll
        for (int j = 0; j < 4; ++j)
            #pragma unroll
            for (int kk = 0; kk < 5; ++kk)
                ac2[j][kk] += wv[j].x*gv[kk].x + wv[j].y*gv[kk].y + wv[j].z*gv[kk].z + wv[j].w*gv[kk].w;
    }
    #pragma unroll
    for (int j = 0; j < 4; ++j) {
        int r = ro + 16*j;
        float pb = ws[O_P1B + r];
        #pragma unroll
        for (int kk = 0; kk < 5; ++kk) attL[r*21 + kb + kk] = ac2[j][kk] + pb;
    }
    __syncthreads();
    {
        int o = tid;
        float av[KK]; float mx = -3.0e38f;
        #pragma unroll
        for (int k = 0; k < KK; ++k) { av[k] = attL[o*21 + k]; mx = fmaxf(mx, av[k]); }
        float ssum = 0.f;
        #pragma unroll
        for (int k = 0; k < KK; ++k) { av[k] = expf(av[k] - mx); ssum += av[k]; }
        float outv = 0.f;
        #pragma unroll
        for (int k = 0; k < KK; ++k) outv += h1L[o*21 + k] * (av[k]/ssum);
        float* xc1 = ws + O_XC1 + b*83*NN;
        xc1[(19+o)*NN + n] = outv;
        if (tid < 19) xc1[tid*NN + n] = xcL[tid];
    }
}

// ================= xpose1: xc1 [b][83][2048] -> xc1T [b][2048][84] ===========
__global__ __launch_bounds__(256) void xpose1_kernel(float* ws) {
    __shared__ float t[84*129];
    int tid = threadIdx.x;
    int b = blockIdx.x >> 4;
    int n0 = (blockIdx.x & 15) << 7;
    const float* xc1 = ws + O_XC1 + (size_t)b*83*NN;
    for (int i = tid; i < 84*128; i += 256) {
        int c = i >> 7, nn = i & 127;
        t[c*129 + nn] = (c < 83) ? xc1[c*NN + n0 + nn] : 0.f;
    }
    __syncthreads();
    float* xT = ws + O_XC2 + (size_t)b*512*NN;
    for (int i = tid; i < 128*84; i += 256) {
        int nn = i / 84, c = i - nn*84;
        xT[(size_t)(n0+nn)*84 + c] = t[c*129 + nn];
    }
}

// ================= edge2 MFMA =================
__global__ __launch_bounds__(256, 1) void edge2_mfma_kernel(float* ws, const int* idx) {
    __shared__ __align__(16) float sbuf[21504];
    __shared__ float scal[5*256];
    __shared__ int idxL[80];
    ushort16_t* g2b = (ushort16_t*)sbuf;
    ushort16_t* hrb = (ushort16_t*)sbuf;
    float* attL = sbuf;

    int tid = threadIdx.x;
    int b  = blockIdx.x >> 9;
    int ng = blockIdx.x & 511;
    int n0 = ng << 2;

    scal[tid]        = ws[O_BN2SC + tid];
    scal[256 + tid]  = ws[O_BN2SH + tid];
    scal[512 + tid]  = ws[O_P2SC + tid];
    scal[768 + tid]  = ws[O_P2SH + tid];
    scal[1024 + tid] = ws[O_P2B + tid];
    if (tid < 80) idxL[tid] = idx[(b*NN + n0 + tid/20)*KK + (tid%20)] & (NN-1);
    {
        uint32* gz = (uint32*)sbuf;
        for (int i = tid; i < 11840; i += 256) gz[i] = 0;
    }
    __syncthreads();

    const float* xT = ws + O_XC2 + (size_t)b*512*NN;
    for (int i = tid; i < 80*21; i += 256) {
        int col = i / 21, c4 = (i - col*21) * 4;
        int p = col / 20;
        int j = idxL[col];
        float4 nb = *(const float4*)&xT[(size_t)j*84 + c4];
        float4 ce = *(const float4*)&xT[(size_t)(n0+p)*84 + c4];
        ushort16_t* g = g2b + col*296;
        st4bf(g + c4,        nb.x, nb.y, nb.z, nb.w);
        st4bf(g + 88 + c4,   ce.x, ce.y, ce.z, ce.w);
        st4bf(g + 176 + c4,  ce.x-nb.x, ce.y-nb.y, ce.z-nb.z, ce.w-nb.w);
    }
    __syncthreads();

    int lane = tid & 63, wv = tid >> 6;
    int quad = lane >> 4, l15 = lane & 15;
    const ushort16_t* w2b  = (const ushort16_t*)(ws + O_W2B16);
    const ushort16_t* p2wb = (const ushort16_t*)(ws + O_P2W16);

    floatx4 acc[4][5];
    #pragma unroll
    for (int mt = 0; mt < 4; ++mt)
        #pragma unroll
        for (int nt = 0; nt < 5; ++nt) acc[mt][nt] = (floatx4){0.f,0.f,0.f,0.f};

    for (int kt = 0; kt < 9; ++kt) {
        int c0 = kt*32 + quad*8;
        short8 a[4], bb[5];
        #pragma unroll
        for (int mt = 0; mt < 4; ++mt)
            a[mt] = *(const short8*)&w2b[(wv*64 + mt*16 + l15)*288 + c0];
        #pragma unroll
        for (int nt = 0; nt < 5; ++nt)
            bb[nt] = *(const short8*)&g2b[(nt*16 + l15)*296 + c0];
        #pragma unroll
        for (int mt = 0; mt < 4; ++mt)
            #pragma unroll
            for (int nt = 0; nt < 5; ++nt)
                acc[mt][nt] = __builtin_amdgcn_mfma_f32_16x16x32_bf16(a[mt], bb[nt], acc[mt][nt], 0, 0, 0);
    }
    __syncthreads();

    float h2s[4][5][4];
    #pragma unroll
    for (int mt = 0; mt < 4; ++mt) {
        int k0 = wv*64 + mt*16 + quad*4;
        #pragma unroll
        for (int nt = 0; nt < 5; ++nt) {
            int col = nt*16 + l15;
            float hv[4];
            #pragma unroll
            for (int r = 0; r < 4; ++r) {
                int row = k0 + r;
                float v = acc[mt][nt][r]*scal[row] + scal[256+row];
                v = v > 0.f ? v : 0.2f*v;
                h2s[mt][nt][r] = v;
                float h = v*scal[512+row] + scal[768+row];
                hv[r] = fmaxf(h, 0.f);
            }
            st4bf(hrb + col*264 + k0, hv[0], hv[1], hv[2], hv[3]);
        }
    }
    __syncthreads();

    floatx4 acc2[4][5];
    #pragma unroll
    for (int mt = 0; mt < 4; ++mt)
        #pragma unroll
        for (int nt = 0; nt < 5; ++nt) acc2[mt][nt] = (floatx4){0.f,0.f,0.f,0.f};
    for (int kt = 0; kt < 8; ++kt) {
        int c0 = kt*32 + quad*8;
        short8 a[4], bb[5];
        #pragma unroll
        for (int mt = 0; mt < 4; ++mt)
            a[mt] = *(const short8*)&p2wb[(wv*64 + mt*16 + l15)*256 + c0];
        #pragma unroll
        for (int nt = 0; nt < 5; ++nt)
            bb[nt] = *(const short8*)&hrb[(nt*16 + l15)*264 + c0];
        #pragma unroll
        for (int mt = 0; mt < 4; ++mt)
            #pragma unroll
            for (int nt = 0; nt < 5; ++nt)
                acc2[mt][nt] = __builtin_amdgcn_mfma_f32_16x16x32_bf16(a[mt], bb[nt], acc2[mt][nt], 0, 0, 0);
    }
    __syncthreads();

    #pragma unroll
    for (int mt = 0; mt < 4; ++mt) {
        int k0 = wv*64 + mt*16 + quad*4;
        #pragma unroll
        for (int nt = 0; nt < 5; ++nt) {
            int col = nt*16 + l15;
            #pragma unroll
            for (int r = 0; r < 4; ++r) {
                int row = k0 + r;
                attL[row*84 + col] = acc2[mt][nt][r] + scal[1024+row];
            }
        }
    }
    __syncthreads();

    #pragma unroll
    for (int q = 0; q < 4; ++q) {
        int pr = tid + 256*q;
        int row = pr >> 2, p = pr & 3;
        float av[KK]; float mx = -3.0e38f;
        #pragma unroll
        for (int k = 0; k < KK; ++k) { av[k] = attL[row*84 + p*20 + k]; mx = fmaxf(mx, av[k]); }
        float ssum = 0.f;
        #pragma unroll
        for (int k = 0; k < KK; ++k) { av[k] = expf(av[k] - mx); ssum += av[k]; }
        float inv = 1.f / ssum;
        #pragma unroll
        for (int k = 0; k < KK; ++k) attL[row*84 + p*20 + k] = av[k] * inv;
    }
    __syncthreads();

    #pragma unroll
    for (int mt = 0; mt < 4; ++mt) {
        int k0 = wv*64 + mt*16 + quad*4;
        #pragma unroll
        for (int nt = 0; nt < 5; ++nt) {
            int col = nt*16 + l15;
            #pragma unroll
            for (int r = 0; r < 4; ++r)
                attL[(k0+r)*84 + col] *= h2s[mt][nt][r];
        }
    }
    __syncthreads();

    float* xout = ws + O_XC2 + (size_t)b*512*NN;
    #pragma unroll
    for (int q = 0; q < 4; ++q) {
        int pr = tid + 256*q;
        int row = pr >> 2, p = pr & 3;
        float sacc = 0.f;
        #pragma unroll
        for (int k = 0; k < KK; ++k) sacc += attL[row*84 + p*20 + k];
        xout[(size_t)(256+row)*NN + n0 + p] = sacc;
    }
}

// ================= final: out = lrelu(bn3(w3 @ x_c2)) -> fp32 =================
__global__ void final_kernel(const float* ws, float* out) {
    __shared__ __align__(16) float tileF[512*16];
    int tid = threadIdx.x;
    int b = blockIdx.x >> 7;
    int n0 = (blockIdx.x & 127) << 4;
    const float* xc2 = ws + O_XC2 + b*512*NN;
    for (int i = tid; i < 512*16; i += 256) {
        int c = i >> 4, nn = i & 15;
        tileF[i] = xc2[c*NN + n0 + nn];
    }
    __syncthreads();
    const float* w3p = ws + O_W3P;
    int r0 = tid*2, r1 = r0 + 1;
    float acc0[16], acc1[16];
    #pragma unroll
    for (int q = 0; q < 16; ++q) { acc0[q] = 0.f; acc1[q] = 0.f; }
    #pragma unroll 4
    for (int c = 0; c < 512; ++c) {
        float w0 = w3p[r0*512 + c], w1v = w3p[r1*512 + c];
        const float4* tr = (const float4*)&tileF[c*16];
        #pragma unroll
        for (int q = 0; q < 4; ++q) {
            float4 t = tr[q];
            acc0[q*4+0] += w0*t.x;  acc0[q*4+1] += w0*t.y;  acc0[q*4+2] += w0*t.z;  acc0[q*4+3] += w0*t.w;
            acc1[q*4+0] += w1v*t.x; acc1[q*4+1] += w1v*t.y; acc1[q*4+2] += w1v*t.z; acc1[q*4+3] += w1v*t.w;
        }
    }
    float s0 = ws[O_BN3SC + r0], q0 = ws[O_BN3SH + r0];
    float s1 = ws[O_BN3SC + r1], q1 = ws[O_BN3SH + r1];
    float* ob = out + b*512*NN;
    #pragma unroll
    for (int nn = 0; nn < 16; ++nn) {
        float v = acc0[nn]*s0 + q0; v = v > 0.f ? v : 0.2f*v;
        ob[r0*NN + n0 + nn] = v;
        float u = acc1[nn]*s1 + q1; u = u > 0.f ? u : 0.2f*u;
        ob[r1*NN + n0 + nn] = u;
    }
}

extern "C" void kernel_launch(void* const* d_in, const int* in_sizes, int n_in,
                              void* d_out, int out_size, void* d_ws, size_t ws_size,
                              hipStream_t stream) {
    float* ws = (float*)d_ws;
    float* out = (float*)d_out;
    float* pkv = ws + O_PKV;
    int*   pki = (int*)(ws + O_PKI);

    detect_kernel<<<1, 64, 0, stream>>>(d_in[0], (int*)ws + O_FLAG);
    prep_kernel<<<64, 256, 0, stream>>>(d_in[1], d_in[2], d_in[3], d_in[4], d_in[5], d_in[6],
                                        d_in[7], d_in[8], d_in[9], d_in[10], d_in[11], d_in[12],
                                        d_in[13], d_in[14], d_in[15], d_in[16], d_in[17], d_in[18],
                                        d_in[19], d_in[20], d_in[21], ws);
    // lafe = xconv + knn3 (split 8) + attention
    xconv_kernel<<<192, 256, 0, stream>>>(d_in[0], ws);
    knn_part_kernel<3, 19, 256, 8><<<512, 256, 0, stream>>>(ws + O_XMAN, pkv, pki);
    knn_merge_kernel<8><<<64, 256, 0, stream>>>(pkv, pki, (int*)(ws + O_IDX3));  // temp home
    lafe_att_kernel<<<64, 256, 0, stream>>>(ws, (const int*)(ws + O_IDX3));
    // knn on x_manet (C=19)
    knn_part_kernel<19, 19, 256, 2><<<128, 256, 0, stream>>>(ws + O_XMAN, pkv, pki);
    knn_merge_kernel<2><<<64, 256, 0, stream>>>(pkv, pki, (int*)(ws + O_IDX2));
    edge1_kernel<<<BB*NN, 64, 0, stream>>>(ws, (const int*)(ws + O_IDX2));
    // knn on x_c1 (C=83)
    knn_part_kernel<83, 83, 128, 4><<<256, 256, 0, stream>>>(ws + O_XC1, pkv, pki);
    knn_merge_kernel<4><<<64, 256, 0, stream>>>(pkv, pki, (int*)(ws + O_IDX3));
    xpose1_kernel<<<128, 256, 0, stream>>>(ws);
    edge2_mfma_kernel<<<BB*512, 256, 0, stream>>>(ws, (const int*)(ws + O_IDX3));
    mlp_kernel<<<BB*NN, 256, 0, stream>>>(ws);
    final_kernel<<<BB*(NN/16), 256, 0, stream>>>(ws, out);
}

// Round 8
// 2115.239 us; speedup vs baseline: 17.8001x; 1.0617x over previous
//
#include <hip/hip_runtime.h>
#include <hip/hip_bf16.h>
#include <math.h>

typedef __hip_bfloat16 bf16;
typedef unsigned short ushort16_t;
typedef unsigned int uint32;
typedef __attribute__((ext_vector_type(8))) short short8;
typedef __attribute__((ext_vector_type(4))) float floatx4;

#define BB 8
#define NN 2048
#define KK 20

// ---- workspace layout (float offsets) ----
#define O_XMAN  0                        // [8][19][2048]  rows 0..2 = x (fp32), rows 3..18 = lafe out
#define O_XC1   311296                   // [8][83][2048]
#define O_XC2   1671168                  // [8][512][2048] rows 0..255=x_mlp, 256..511=xp2
                                         // reused: knn partial scratch, then xc1T[b][2048][84]
#define O_IDX2  10059776                 // int [8][2048][20]
#define O_IDX3  10387456                 // int [8][2048][20] (also temp home for lafe knn idx)
#define O_MLPW  10715136                 // [256][20] padded
#define O_MLPSC 10720256
#define O_MLPSH 10720512
#define O_W1P   10720768                 // [64][64] padded
#define O_BN1SC 10724864
#define O_BN1SH 10724928
#define O_P1SC  10724992
#define O_P1SH  10725056
#define O_P1W   10725120                 // [64][64]
#define O_P1B   10729216
#define O_W2P   10729280                 // (spare)
#define O_BN2SC 10794816
#define O_BN2SH 10795072
#define O_P2SC  10795328
#define O_P2SH  10795584
#define O_P2W   10795840                 // (spare)
#define O_P2B   10861376
#define O_W3P   10861632                 // [512][512]
#define O_BN3SC 11123776
#define O_BN3SH 11124288
#define O_LA    11124800                 // w1[48] b1[16] w2[48] b2[16] w3[16] b3[1]
#define O_FLAG  11124960                 // int: 1 if inputs are fp32, 0 if bf16
#define O_W2B16 11125760                 // ushort [256][288] bf16 w2, segment-padded
#define O_P2W16 11162624                 // ushort [256][256] bf16 p2w

// knn partial scratch inside XC2 region (consumed before xpose/mlp/edge2 write XC2)
// sized for S=8: [8][8][2048][20] = 2,621,440 each; pv+pi end at 6,914,048 < O_IDX2
#define O_PKV   O_XC2
#define O_PKI   (O_XC2 + 2621440)

__device__ __forceinline__ float ldin(const void* p, int i, int f32) {
    return f32 ? ((const float*)p)[i]
               : __bfloat162float(((const bf16*)p)[i]);
}

__device__ __forceinline__ ushort16_t f2bf(float v) {
    union { bf16 h; ushort16_t u; } x; x.h = __float2bfloat16(v); return x.u;
}

__device__ __forceinline__ void st4bf(ushort16_t* p, float a, float b, float c, float d) {
    uint2 v;
    v.x = (uint32)f2bf(a) | ((uint32)f2bf(b) << 16);
    v.y = (uint32)f2bf(c) | ((uint32)f2bf(d) << 16);
    *(uint2*)p = v;
}

// top-k insertion, compile-time indices only (VGPR-resident with __launch_bounds__)
__device__ __forceinline__ void topk_ins(float (&tv)[KK], int (&ti)[KK], float d, int m) {
    if (d > tv[KK-1]) {
        tv[KK-1] = d; ti[KK-1] = m;
        #pragma unroll
        for (int j = KK-1; j > 0; --j) {
            if (tv[j] > tv[j-1]) {
                float tf = tv[j-1]; tv[j-1] = tv[j]; tv[j] = tf;
                int   tx = ti[j-1]; ti[j-1] = ti[j]; ti[j] = tx;
            }
        }
    }
}

// ============ detect: are inputs fp32 or bf16? ============
__global__ void detect_kernel(const void* x, int* flag) {
    if (threadIdx.x == 0 && blockIdx.x == 0) {
        const unsigned short* u = (const unsigned short*)x;
        int bad = 0;
        for (int i = 0; i < 64; ++i) {
            int e = (u[i] >> 7) & 0xFF;
            if (e >= 0x86) bad++;
        }
        *flag = (bad > 0) ? 1 : 0;
    }
}

// ================= prep =================
__global__ void prep_kernel(
    const void* la_w1, const void* la_b1, const void* la_w2, const void* la_b2,
    const void* la_w3, const void* la_b3,
    const void* mlp_w, const void* mlp_b, const void* mlp_bn,
    const void* w1, const void* bn1, const void* w2, const void* bn2,
    const void* w3, const void* bn3,
    const void* p1_bn, const void* p1_w, const void* p1_b,
    const void* p2_bn, const void* p2_w, const void* p2_b,
    float* ws)
{
    const int f32 = ((const int*)ws)[O_FLAG];
    int gid = blockIdx.x * blockDim.x + threadIdx.x;
    int gsz = gridDim.x * blockDim.x;

    for (int i = gid; i < 256*20; i += gsz) {
        int o = i / 20, c = i - o*20;
        ws[O_MLPW + i] = (c < 19) ? ldin(mlp_w, o*19 + c, f32) : 0.f;
    }
    for (int c = gid; c < 256; c += gsz) {
        float g = ldin(mlp_bn, c, f32), be = ldin(mlp_bn, 256+c, f32);
        float m = ldin(mlp_bn, 512+c, f32), vv = ldin(mlp_bn, 768+c, f32);
        float s = g / sqrtf(vv + 1e-5f);
        ws[O_MLPSC + c] = s;
        ws[O_MLPSH + c] = be + (ldin(mlp_b, c, f32) - m) * s;
    }
    for (int i = gid; i < 64*64; i += gsz) {
        int o = i >> 6, c = i & 63;
        ws[O_W1P + i] = (c < 57) ? ldin(w1, o*57 + c, f32) : 0.f;
    }
    for (int c = gid; c < 64; c += gsz) {
        float g = ldin(bn1, c, f32), be = ldin(bn1, 64+c, f32);
        float m = ldin(bn1, 128+c, f32), vv = ldin(bn1, 192+c, f32);
        float s = g / sqrtf(vv + 1e-5f);
        ws[O_BN1SC + c] = s; ws[O_BN1SH + c] = be - m*s;
        float g2 = ldin(p1_bn, c, f32), be2 = ldin(p1_bn, 64+c, f32);
        float m2 = ldin(p1_bn, 128+c, f32), vv2 = ldin(p1_bn, 192+c, f32);
        float s2 = g2 / sqrtf(vv2 + 1e-5f);
        ws[O_P1SC + c] = s2; ws[O_P1SH + c] = be2 - m2*s2;
        ws[O_P1B + c] = ldin(p1_b, c, f32);
    }
    for (int i = gid; i < 64*64; i += gsz) ws[O_P1W + i] = ldin(p1_w, i, f32);
    for (int c = gid; c < 256; c += gsz) {
        float g = ldin(bn2, c, f32), be = ldin(bn2, 256+c, f32);
        float m = ldin(bn2, 512+c, f32), vv = ldin(bn2, 768+c, f32);
        float s = g / sqrtf(vv + 1e-5f);
        ws[O_BN2SC + c] = s; ws[O_BN2SH + c] = be - m*s;
        float g2 = ldin(p2_bn, c, f32), be2 = ldin(p2_bn, 256+c, f32);
        float m2 = ldin(p2_bn, 512+c, f32), vv2 = ldin(p2_bn, 768+c, f32);
        float s2 = g2 / sqrtf(vv2 + 1e-5f);
        ws[O_P2SC + c] = s2; ws[O_P2SH + c] = be2 - m2*s2;
        ws[O_P2B + c] = ldin(p2_b, c, f32);
    }
    for (int i = gid; i < 512*512; i += gsz) ws[O_W3P + i] = ldin(w3, i, f32);
    for (int c = gid; c < 512; c += gsz) {
        float g = ldin(bn3, c, f32), be = ldin(bn3, 512+c, f32);
        float m = ldin(bn3, 1024+c, f32), vv = ldin(bn3, 1536+c, f32);
        float s = g / sqrtf(vv + 1e-5f);
        ws[O_BN3SC + c] = s; ws[O_BN3SH + c] = be - m*s;
    }
    for (int i = gid; i < 48; i += gsz) ws[O_LA + i]       = ldin(la_w1, i, f32);
    for (int i = gid; i < 16; i += gsz) ws[O_LA + 48 + i]  = ldin(la_b1, i, f32);
    for (int i = gid; i < 48; i += gsz) ws[O_LA + 64 + i]  = ldin(la_w2, i, f32);
    for (int i = gid; i < 16; i += gsz) ws[O_LA + 112 + i] = ldin(la_b2, i, f32);
    for (int i = gid; i < 16; i += gsz) ws[O_LA + 128 + i] = ldin(la_w3, i, f32);
    if (gid == 0) ws[O_LA + 144] = ldin(la_b3, 0, f32);

    // bf16 weights for edge2 MFMA (w2b: [256][288] segment-padded 83->88)
    ushort16_t* w2b = (ushort16_t*)(ws + O_W2B16);
    for (int i = gid; i < 256*288; i += gsz) {
        int row = i / 288, cp = i - row*288;
        int s = cp / 88, cc = cp - s*88;
        float v = (s < 3 && cc < 83) ? ldin(w2, row*249 + s*83 + cc, f32) : 0.f;
        w2b[i] = f2bf(v);
    }
    ushort16_t* pwb = (ushort16_t*)(ws + O_P2W16);
    for (int i = gid; i < 256*256; i += gsz) pwb[i] = f2bf(ldin(p2_w, i, f32));
}

// ================= xconv: x -> fp32 into XMAN rows 0..2 =================
__global__ __launch_bounds__(256) void xconv_kernel(const void* x, float* ws) {
    const int f32 = ((const int*)ws)[O_FLAG];
    int gid = blockIdx.x*256 + threadIdx.x;     // 0 .. 8*3*2048-1
    int b = gid / (3*NN), r = gid - b*3*NN;
    ws[O_XMAN + b*19*NN + r] = ldin(x, gid, f32);
}

// ====== knn partial: C channels, row-stride CS, split S over candidates ======
template<int C, int CS, int TILE, int S>
__global__ __launch_bounds__(256, 1) void knn_part_kernel(const float* feat, float* pv, int* pi) {
    __shared__ __align__(16) float tile[C * TILE + TILE];
    float* xxt = tile + C * TILE;
    int tid = threadIdx.x;
    int s = blockIdx.x & (S-1);
    int bc = blockIdx.x / S;
    int b = bc >> 3;
    int n = ((bc & 7) << 8) + tid;
    const float* fb = feat + b * CS * NN;
    float myf[C];
    #pragma unroll
    for (int c = 0; c < C; ++c) myf[c] = fb[c*NN + n];
    float xxn = 0.f;
    #pragma unroll
    for (int c = 0; c < C; ++c) xxn += myf[c]*myf[c];
    float tv[KK]; int ti[KK];
    #pragma unroll
    for (int k = 0; k < KK; ++k) { tv[k] = -3.0e38f; ti[k] = 0; }
    const int T0 = s * (NN / S / TILE), T1 = (s+1) * (NN / S / TILE);
    for (int t = T0; t < T1; ++t) {
        __syncthreads();
        for (int i = tid; i < C*TILE; i += 256) {
            int c = i / TILE, j = i - c*TILE;
            tile[i] = fb[c*NN + t*TILE + j];
        }
        __syncthreads();
        for (int j = tid; j < TILE; j += 256) {
            float sq = 0.f;
            #pragma unroll
            for (int c = 0; c < C; ++c) sq += tile[c*TILE + j]*tile[c*TILE + j];
            xxt[j] = sq;
        }
        __syncthreads();
        for (int j4 = 0; j4 < TILE/4; ++j4) {
            float4 dot = make_float4(0.f, 0.f, 0.f, 0.f);
            #pragma unroll
            for (int c = 0; c < C; ++c) {
                float4 tvv = *(const float4*)&tile[c*TILE + j4*4];
                float f = myf[c];
                dot.x += f*tvv.x; dot.y += f*tvv.y; dot.z += f*tvv.z; dot.w += f*tvv.w;
            }
            float4 xxv = *(const float4*)&xxt[j4*4];
            int mb = t*TILE + j4*4;
            topk_ins(tv, ti, 2.f*dot.x - xxn - xxv.x, mb+0);
            topk_ins(tv, ti, 2.f*dot.y - xxn - xxv.y, mb+1);
            topk_ins(tv, ti, 2.f*dot.z - xxn - xxv.z, mb+2);
            topk_ins(tv, ti, 2.f*dot.w - xxn - xxv.w, mb+3);
        }
    }
    long base = ((long)(s*BB + b)*NN + n)*KK;
    #pragma unroll
    for (int k = 0; k < KK; ++k) { pv[base + k] = tv[k]; pi[base + k] = ti[k]; }
}

template<int S>
__global__ __launch_bounds__(256, 1) void knn_merge_kernel(const float* pv, const int* pi, int* idxout) {
    int gid = blockIdx.x*256 + threadIdx.x;
    float tv[KK]; int ti[KK];
    #pragma unroll
    for (int k = 0; k < KK; ++k) { tv[k] = -3.0e38f; ti[k] = 0; }
    #pragma unroll
    for (int s = 0; s < S; ++s) {
        long base = ((long)s*BB*NN + gid)*KK;
        #pragma unroll
        for (int k = 0; k < KK; ++k)
            topk_ins(tv, ti, pv[base + k], pi[base + k]);
    }
    #pragma unroll
    for (int k = 0; k < KK; ++k) idxout[(long)gid*KK + k] = ti[k];
}

// ================= lafe attention (post-knn) =================
__global__ __launch_bounds__(256, 1) void lafe_att_kernel(float* ws, const int* idx) {
    __shared__ float xs0[NN], xs1[NN], xs2[NN];
    int tid = threadIdx.x;
    int b = blockIdx.x >> 3;
    int n = ((blockIdx.x & 7) << 8) + tid;
    float* xm = ws + O_XMAN + b*19*NN;
    for (int i = tid; i < NN; i += 256) {
        xs0[i] = xm[i]; xs1[i] = xm[NN + i]; xs2[i] = xm[2*NN + i];
    }
    __syncthreads();
    float a0 = xs0[n], a1 = xs1[n], a2 = xs2[n];
    int ti[KK];
    #pragma unroll
    for (int k = 0; k < KK; ++k) ti[k] = idx[(b*NN + n)*KK + k] & (NN-1);
    const float* wl = ws + O_LA;
    float sa = wl[144];
    #pragma unroll
    for (int o = 0; o < 16; ++o) {
        float nf = wl[o*3+0]*a0 + wl[o*3+1]*a1 + wl[o*3+2]*a2 + wl[48+o];
        sa += wl[128+o]*nf;
    }
    float lg[KK]; float mx = -3.0e38f;
    #pragma unroll
    for (int k = 0; k < KK; ++k) {
        int m = ti[k];
        float d0 = a0 - xs0[m], d1 = a1 - xs1[m], d2 = a2 - xs2[m];
        float na = wl[144];
        #pragma unroll
        for (int o = 0; o < 16; ++o) {
            float ef = wl[64+o*3+0]*d0 + wl[64+o*3+1]*d1 + wl[64+o*3+2]*d2 + wl[112+o];
            na += wl[128+o]*ef;
        }
        float t = sa + na;
        t = t > 0.f ? t : 0.01f*t;
        lg[k] = t; mx = fmaxf(mx, t);
    }
    float ssum = 0.f;
    #pragma unroll
    for (int k = 0; k < KK; ++k) { lg[k] = expf(lg[k] - mx); ssum += lg[k]; }
    float vals[16];
    #pragma unroll
    for (int o = 0; o < 16; ++o) vals[o] = 0.f;
    #pragma unroll
    for (int k = 0; k < KK; ++k) {
        float coef = lg[k] / ssum;
        int m = ti[k];
        float d0 = a0 - xs0[m], d1 = a1 - xs1[m], d2 = a2 - xs2[m];
        #pragma unroll
        for (int o = 0; o < 16; ++o) {
            float ef = wl[64+o*3+0]*d0 + wl[64+o*3+1]*d1 + wl[64+o*3+2]*d2 + wl[112+o];
            vals[o] += coef * ef;
        }
    }
    #pragma unroll
    for (int o = 0; o < 16; ++o) {
        float v = vals[o];
        xm[(3+o)*NN + n] = v > 0.f ? v : expm1f(v);
    }
}

// ================= mlp =================
__global__ void mlp_kernel(float* ws) {
    __shared__ __align__(16) float xv[20];
    int tid = threadIdx.x;
    int b = blockIdx.x >> 11, n = blockIdx.x & 2047;
    if (tid < 20) xv[tid] = (tid < 19) ? ws[O_XMAN + b*19*NN + tid*NN + n] : 0.f;
    __syncthreads();
    const float* mw = ws + O_MLPW;
    float acc = 0.f;
    #pragma unroll
    for (int c4 = 0; c4 < 5; ++c4) {
        float4 w = *(const float4*)&mw[tid*20 + c4*4];
        float4 g = *(const float4*)&xv[c4*4];
        acc += w.x*g.x + w.y*g.y + w.z*g.z + w.w*g.w;
    }
    float v = acc * ws[O_MLPSC + tid] + ws[O_MLPSH + tid];
    ws[O_XC2 + b*512*NN + tid*NN + n] = fmaxf(v, 0.f);
}

// ================= edge1 (fp32) =================
__global__ void edge1_kernel(float* ws, const int* idx) {
    __shared__ __align__(16) float g1T[KK*64];
    __shared__ __align__(16) float h1L[64*21];
    __shared__ __align__(16) float hrT[KK*64];
    __shared__ __align__(16) float attL[64*21];
    __shared__ float xcL[19];
    __shared__ int idxL[KK];
    int tid = threadIdx.x;
    int b = blockIdx.x >> 11, n = blockIdx.x & 2047;
    const float* xb = ws + O_XMAN + b*19*NN;
    if (tid < KK) idxL[tid] = idx[(b*NN + n)*KK + tid] & (NN-1);
    if (tid < 19) xcL[tid] = xb[tid*NN + n];
    __syncthreads();
    for (int i = tid; i < KK*64; i += 64) {
        int k = i >> 6, c = i & 63;
        int j = idxL[k];
        float v = 0.f;
        if (c < 19) v = xb[c*NN + j];
        else if (c < 38) v = xcL[c-19];
        else if (c < 57) v = xcL[c-38] - xb[(c-38)*NN + j];
        g1T[i] = v;
    }
    __syncthreads();
    int ro = tid & 15, kb = (tid >> 4) * 5;
    const float* w1p = ws + O_W1P;
    float acc[4][5];
    #pragma unroll
    for (int j = 0; j < 4; ++j)
        #pragma unroll
        for (int kk = 0; kk < 5; ++kk) acc[j][kk] = 0.f;
    for (int c4 = 0; c4 < 16; ++c4) {
        float4 gv[5], wv[4];
        #pragma unroll
        for (int kk = 0; kk < 5; ++kk) gv[kk] = *(const float4*)&g1T[(kb+kk)*64 + c4*4];
        #pragma unroll
        for (int j = 0; j < 4; ++j) wv[j] = *(const float4*)&w1p[(ro + 16*j)*64 + c4*4];
        #pragma unroll
        for (int j = 0; j < 4; ++j)
            #pragma unroll
            for (int kk = 0; kk < 5; ++kk)
                acc[j][kk] += wv[j].x*gv[kk].x + wv[j].y*gv[kk].y + wv[j].z*gv[kk].z + wv[j].w*gv[kk].w;
    }
    #pragma unroll
    for (int j = 0; j < 4; ++j) {
        int r = ro + 16*j;
        float s1 = ws[O_BN1SC + r], h1s = ws[O_BN1SH + r];
        float ps = ws[O_P1SC + r], ph = ws[O_P1SH + r];
        #pragma unroll
        for (int kk = 0; kk < 5; ++kk) {
            float v = acc[j][kk]*s1 + h1s;
            v = v > 0.f ? v : 0.2f*v;
            h1L[r*21 + kb + kk] = v;
            float hv = v*ps + ph;
            hrT[(kb+kk)*64 + r] = hv > 0.f ? hv : 0.f;
        }
    }
    __syncthreads();
    const float* p1w = ws + O_P1W;
    float ac2[4][5];
    #pragma unroll
    for (int j = 0; j < 4; ++j)
        #pragma unroll
        for (int kk = 0; kk < 5; ++kk) ac2[j][kk] = 0.f;
    for (int c4 = 0; c4 < 16; ++c4) {
        float4 gv[5], wv[4];
        #pragma unroll
        for (int kk = 0; kk < 5; ++kk) gv[kk] = *(const float4*)&hrT[(kb+kk)*64 + c4*4];
        #pragma unroll
        for (int j = 0; j < 4; ++j) wv[j] = *(const float4*)&p1w[(ro + 16*j)*64 + c4*4];
        #pragma unroll
        for (int j = 0; j < 4; ++j)
            #pragma unroll
            for (int kk = 0; kk < 5; ++kk)
                ac2[j][kk] += wv[j].x*gv[kk].x + wv[j].y*gv[kk].y + wv[j].z*gv[kk].z + wv[j].w*gv[kk].w;
    }
    #pragma unroll
    for (int j = 0; j < 4; ++j) {
        int r = ro + 16*j;
        float pb = ws[O_P1B + r];
        #pragma unroll
        for (int kk = 0; kk < 5; ++kk) attL[r*21 + kb + kk] = ac2[j][kk] + pb;
    }
    __syncthreads();
    {
        int o = tid;
        float av[KK]; float mx = -3.0e38f;
        #pragma unroll
        for (int k = 0; k < KK; ++k) { av[k] = attL[o*21 + k]; mx = fmaxf(mx, av[k]); }
        float ssum = 0.f;
        #pragma unroll
        for (int k = 0; k < KK; ++k) { av[k] = expf(av[k] - mx); ssum += av[k]; }
        float outv = 0.f;
        #pragma unroll
        for (int k = 0; k < KK; ++k) outv += h1L[o*21 + k] * (av[k]/ssum);
        float* xc1 = ws + O_XC1 + b*83*NN;
        xc1[(19+o)*NN + n] = outv;
        if (tid < 19) xc1[tid*NN + n] = xcL[tid];
    }
}

// ================= xpose1: xc1 [b][83][2048] -> xc1T [b][2048][84] ===========
__global__ __launch_bounds__(256) void xpose1_kernel(float* ws) {
    __shared__ float t[84*129];
    int tid = threadIdx.x;
    int b = blockIdx.x >> 4;
    int n0 = (blockIdx.x & 15) << 7;
    const float* xc1 = ws + O_XC1 + (size_t)b*83*NN;
    for (int i = tid; i < 84*128; i += 256) {
        int c = i >> 7, nn = i & 127;
        t[c*129 + nn] = (c < 83) ? xc1[c*NN + n0 + nn] : 0.f;
    }
    __syncthreads();
    float* xT = ws + O_XC2 + (size_t)b*512*NN;
    for (int i = tid; i < 128*84; i += 256) {
        int nn = i / 84, c = i - nn*84;
        xT[(size_t)(n0+nn)*84 + c] = t[c*129 + nn];
    }
}

// ================= edge2 MFMA =================
__global__ __launch_bounds__(256, 1) void edge2_mfma_kernel(float* ws, const int* idx) {
    __shared__ __align__(16) float sbuf[21504];
    __shared__ float scal[5*256];
    __shared__ int idxL[80];
    ushort16_t* g2b = (ushort16_t*)sbuf;
    ushort16_t* hrb = (ushort16_t*)sbuf;
    float* attL = sbuf;

    int tid = threadIdx.x;
    int b  = blockIdx.x >> 9;
    int ng = blockIdx.x & 511;
    int n0 = ng << 2;

    scal[tid]        = ws[O_BN2SC + tid];
    scal[256 + tid]  = ws[O_BN2SH + tid];
    scal[512 + tid]  = ws[O_P2SC + tid];
    scal[768 + tid]  = ws[O_P2SH + tid];
    scal[1024 + tid] = ws[O_P2B + tid];
    if (tid < 80) idxL[tid] = idx[(b*NN + n0 + tid/20)*KK + (tid%20)] & (NN-1);
    {
        uint32* gz = (uint32*)sbuf;
        for (int i = tid; i < 11840; i += 256) gz[i] = 0;
    }
    __syncthreads();

    const float* xT = ws + O_XC2 + (size_t)b*512*NN;
    for (int i = tid; i < 80*21; i += 256) {
        int col = i / 21, c4 = (i - col*21) * 4;
        int p = col / 20;
        int j = idxL[col];
        float4 nb = *(const float4*)&xT[(size_t)j*84 + c4];
        float4 ce = *(const float4*)&xT[(size_t)(n0+p)*84 + c4];
        ushort16_t* g = g2b + col*296;
        st4bf(g + c4,        nb.x, nb.y, nb.z, nb.w);
        st4bf(g + 88 + c4,   ce.x, ce.y, ce.z, ce.w);
        st4bf(g + 176 + c4,  ce.x-nb.x, ce.y-nb.y, ce.z-nb.z, ce.w-nb.w);
    }
    __syncthreads();

    int lane = tid & 63, wv = tid >> 6;
    int quad = lane >> 4, l15 = lane & 15;
    const ushort16_t* w2b  = (const ushort16_t*)(ws + O_W2B16);
    const ushort16_t* p2wb = (const ushort16_t*)(ws + O_P2W16);

    floatx4 acc[4][5];
    #pragma unroll
    for (int mt = 0; mt < 4; ++mt)
        #pragma unroll
        for (int nt = 0; nt < 5; ++nt) acc[mt][nt] = (floatx4){0.f,0.f,0.f,0.f};

    for (int kt = 0; kt < 9; ++kt) {
        int c0 = kt*32 + quad*8;
        short8 a[4], bb[5];
        #pragma unroll
        for (int mt = 0; mt < 4; ++mt)
            a[mt] = *(const short8*)&w2b[(wv*64 + mt*16 + l15)*288 + c0];
        #pragma unroll
        for (int nt = 0; nt < 5; ++nt)
            bb[nt] = *(const short8*)&g2b[(nt*16 + l15)*296 + c0];
        #pragma unroll
        for (int mt = 0; mt < 4; ++mt)
            #pragma unroll
            for (int nt = 0; nt < 5; ++nt)
                acc[mt][nt] = __builtin_amdgcn_mfma_f32_16x16x32_bf16(a[mt], bb[nt], acc[mt][nt], 0, 0, 0);
    }
    __syncthreads();

    float h2s[4][5][4];
    #pragma unroll
    for (int mt = 0; mt < 4; ++mt) {
        int k0 = wv*64 + mt*16 + quad*4;
        #pragma unroll
        for (int nt = 0; nt < 5; ++nt) {
            int col = nt*16 + l15;
            float hv[4];
            #pragma unroll
            for (int r = 0; r < 4; ++r) {
                int row = k0 + r;
                float v = acc[mt][nt][r]*scal[row] + scal[256+row];
                v = v > 0.f ? v : 0.2f*v;
                h2s[mt][nt][r] = v;
                float h = v*scal[512+row] + scal[768+row];
                hv[r] = fmaxf(h, 0.f);
            }
            st4bf(hrb + col*264 + k0, hv[0], hv[1], hv[2], hv[3]);
        }
    }
    __syncthreads();

    floatx4 acc2[4][5];
    #pragma unroll
    for (int mt = 0; mt < 4; ++mt)
        #pragma unroll
        for (int nt = 0; nt < 5; ++nt) acc2[mt][nt] = (floatx4){0.f,0.f,0.f,0.f};
    for (int kt = 0; kt < 8; ++kt) {
        int c0 = kt*32 + quad*8;
        short8 a[4], bb[5];
        #pragma unroll
        for (int mt = 0; mt < 4; ++mt)
            a[mt] = *(const short8*)&p2wb[(wv*64 + mt*16 + l15)*256 + c0];
        #pragma unroll
        for (int nt = 0; nt < 5; ++nt)
            bb[nt] = *(const short8*)&hrb[(nt*16 + l15)*264 + c0];
        #pragma unroll
        for (int mt = 0; mt < 4; ++mt)
            #pragma unroll
            for (int nt = 0; nt < 5; ++nt)
                acc2[mt][nt] = __builtin_amdgcn_mfma_f32_16x16x32_bf16(a[mt], bb[nt], acc2[mt][nt], 0, 0, 0);
    }
    __syncthreads();

    #pragma unroll
    for (int mt = 0; mt < 4; ++mt) {
        int k0 = wv*64 + mt*16 + quad*4;
        #pragma unroll
        for (int nt = 0; nt < 5; ++nt) {
            int col = nt*16 + l15;
            #pragma unroll
            for (int r = 0; r < 4; ++r) {
                int row = k0 + r;
                attL[row*84 + col] = acc2[mt][nt][r] + scal[1024+row];
            }
        }
    }
    __syncthreads();

    #pragma unroll
    for (int q = 0; q < 4; ++q) {
        int pr = tid + 256*q;
        int row = pr >> 2, p = pr & 3;
        float av[KK]; float mx = -3.0e38f;
        #pragma unroll
        for (int k = 0; k < KK; ++k) { av[k] = attL[row*84 + p*20 + k]; mx = fmaxf(mx, av[k]); }
        float ssum = 0.f;
        #pragma unroll
        for (int k = 0; k < KK; ++k) { av[k] = expf(av[k] - mx); ssum += av[k]; }
        float inv = 1.f / ssum;
        #pragma unroll
        for (int k = 0; k < KK; ++k) attL[row*84 + p*20 + k] = av[k] * inv;
    }
    __syncthreads();

    #pragma unroll
    for (int mt = 0; mt < 4; ++mt) {
        int k0 = wv*64 + mt*16 + quad*4;
        #pragma unroll
        for (int nt = 0; nt < 5; ++nt) {
            int col = nt*16 + l15;
            #pragma unroll
            for (int r = 0; r < 4; ++r)
                attL[(k0+r)*84 + col] *= h2s[mt][nt][r];
        }
    }
    __syncthreads();

    float* xout = ws + O_XC2 + (size_t)b*512*NN;
    #pragma unroll
    for (int q = 0; q < 4; ++q) {
        int pr = tid + 256*q;
        int row = pr >> 2, p = pr & 3;
        float sacc = 0.f;
        #pragma unroll
        for (int k = 0; k < KK; ++k) sacc += attL[row*84 + p*20 + k];
        xout[(size_t)(256+row)*NN + n0 + p] = sacc;
    }
}

// ================= final: out = lrelu(bn3(w3 @ x_c2)) -> fp32 =================
__global__ void final_kernel(const float* ws, float* out) {
    __shared__ __align__(16) float tileF[512*16];
    int tid = threadIdx.x;
    int b = blockIdx.x >> 7;
    int n0 = (blockIdx.x & 127) << 4;
    const float* xc2 = ws + O_XC2 + b*512*NN;
    for (int i = tid; i < 512*16; i += 256) {
        int c = i >> 4, nn = i & 15;
        tileF[i] = xc2[c*NN + n0 + nn];
    }
    __syncthreads();
    const float* w3p = ws + O_W3P;
    int r0 = tid*2, r1 = r0 + 1;
    float acc0[16], acc1[16];
    #pragma unroll
    for (int q = 0; q < 16; ++q) { acc0[q] = 0.f; acc1[q] = 0.f; }
    #pragma unroll 4
    for (int c = 0; c < 512; ++c) {
        float w0 = w3p[r0*512 + c], w1v = w3p[r1*512 + c];
        const float4* tr = (const float4*)&tileF[c*16];
        #pragma unroll
        for (int q = 0; q < 4; ++q) {
            float4 t = tr[q];
            acc0[q*4+0] += w0*t.x;  acc0[q*4+1] += w0*t.y;  acc0[q*4+2] += w0*t.z;  acc0[q*4+3] += w0*t.w;
            acc1[q*4+0] += w1v*t.x; acc1[q*4+1] += w1v*t.y; acc1[q*4+2] += w1v*t.z; acc1[q*4+3] += w1v*t.w;
        }
    }
    float s0 = ws[O_BN3SC + r0], q0 = ws[O_BN3SH + r0];
    float s1 = ws[O_BN3SC + r1], q1 = ws[O_BN3SH + r1];
    float* ob = out + b*512*NN;
    #pragma unroll
    for (int nn = 0; nn < 16; ++nn) {
        float v = acc0[nn]*s0 + q0; v = v > 0.f ? v : 0.2f*v;
        ob[r0*NN + n0 + nn] = v;
        float u = acc1[nn]*s1 + q1; u = u > 0.f ? u : 0.2f*u;
        ob[r1*NN + n0 + nn] = u;
    }
}

extern "C" void kernel_launch(void* const* d_in, const int* in_sizes, int n_in,
                              void* d_out, int out_size, void* d_ws, size_t ws_size,
                              hipStream_t stream) {
    float* ws = (float*)d_ws;
    float* out = (float*)d_out;
    float* pkv = ws + O_PKV;
    int*   pki = (int*)(ws + O_PKI);

    detect_kernel<<<1, 64, 0, stream>>>(d_in[0], (int*)ws + O_FLAG);
    prep_kernel<<<64, 256, 0, stream>>>(d_in[1], d_in[2], d_in[3], d_in[4], d_in[5], d_in[6],
                                        d_in[7], d_in[8], d_in[9], d_in[10], d_in[11], d_in[12],
                                        d_in[13], d_in[14], d_in[15], d_in[16], d_in[17], d_in[18],
                                        d_in[19], d_in[20], d_in[21], ws);
    // lafe = xconv + knn3 (split 8) + attention
    xconv_kernel<<<192, 256, 0, stream>>>(d_in[0], ws);
    knn_part_kernel<3, 19, 256, 8><<<512, 256, 0, stream>>>(ws + O_XMAN, pkv, pki);
    knn_merge_kernel<8><<<64, 256, 0, stream>>>(pkv, pki, (int*)(ws + O_IDX3));  // temp home
    lafe_att_kernel<<<64, 256, 0, stream>>>(ws, (const int*)(ws + O_IDX3));
    // knn on x_manet (C=19), split 8
    knn_part_kernel<19, 19, 256, 8><<<512, 256, 0, stream>>>(ws + O_XMAN, pkv, pki);
    knn_merge_kernel<8><<<64, 256, 0, stream>>>(pkv, pki, (int*)(ws + O_IDX2));
    edge1_kernel<<<BB*NN, 64, 0, stream>>>(ws, (const int*)(ws + O_IDX2));
    // knn on x_c1 (C=83), split 8
    knn_part_kernel<83, 83, 128, 8><<<512, 256, 0, stream>>>(ws + O_XC1, pkv, pki);
    knn_merge_kernel<8><<<64, 256, 0, stream>>>(pkv, pki, (int*)(ws + O_IDX3));
    xpose1_kernel<<<128, 256, 0, stream>>>(ws);
    edge2_mfma_kernel<<<BB*512, 256, 0, stream>>>(ws, (const int*)(ws + O_IDX3));
    mlp_kernel<<<BB*NN, 256, 0, stream>>>(ws);
    final_kernel<<<BB*(NN/16), 256, 0, stream>>>(ws, out);
}